// Round 2
// baseline (15162.181 us; speedup 1.0000x reference)
//
#include <hip/hip_runtime.h>
#include <math.h>

// ---------------------------------------------------------------------------
// VQ-VAE forward, fp32, round 1: fix 4-byte workspace overflow (lac now lives
// inside the reused h2 region; ws_size-adaptive chunked fallback).
// Encoder: conv(3->64,k4,s2,p1)+relu -> conv(64->128,k4,s2,p1)+relu
//          -> conv(128->64,k3,s1,p1)+relu
// VQ: argmin over 512 codes (D=64), loss = 1.25*mean((q-z)^2)
// Decoder: deconvT(64->128,k4,s2,p1)+relu -> deconvT(128->64,k4,s2,p1)+relu
//          -> deconvT(64->3,k3,s1,p1)+sigmoid
// ---------------------------------------------------------------------------

__global__ void zero_k(float* __restrict__ p) { p[0] = 0.f; }

// conv1: x(c,3,256,256) -> h1(c,64,128,128). 1 thread = 1 output.
__global__ __launch_bounds__(256) void conv1_k(
    const float* __restrict__ x, const float* __restrict__ w,
    const float* __restrict__ bias, float* __restrict__ out)
{
    int idx = blockIdx.x * 256 + threadIdx.x;   // c * 1,048,576 threads
    int ow = idx & 127;
    int oh = (idx >> 7) & 127;
    int co = (idx >> 14) & 63;
    int b  = idx >> 20;
    float acc = bias[co];
    int ih0 = oh * 2 - 1, iw0 = ow * 2 - 1;
    for (int ci = 0; ci < 3; ++ci) {
        const float* xp = x + ((size_t)(b * 3 + ci) * 256) * 256;
        const float* wp = w + (co * 3 + ci) * 16;
        for (int kh = 0; kh < 4; ++kh) {
            int ih = ih0 + kh;
            if ((unsigned)ih >= 256u) continue;
            const float* row = xp + ih * 256;
            for (int kw = 0; kw < 4; ++kw) {
                int iw = iw0 + kw;
                if ((unsigned)iw >= 256u) continue;
                acc = fmaf(row[iw], wp[kh * 4 + kw], acc);
            }
        }
    }
    out[idx] = fmaxf(acc, 0.f);
}

// conv2: h1(c,64,128,128) -> h2(c,128,64,64). Thread = 2co x 4ow.
__global__ __launch_bounds__(256) void conv2_k(
    const float* __restrict__ in, const float* __restrict__ w,
    const float* __restrict__ bias, float* __restrict__ out)
{
    int T = blockIdx.x * 256 + threadIdx.x;     // c * 65,536 threads
    int owq = T & 15;
    int oh  = (T >> 4) & 63;
    int co0 = (T >> 10) & 63;
    int b   = T >> 16;
    int ow0 = owq * 4;
    float accA[4], accB[4];
    float bA = bias[co0], bB = bias[co0 + 64];
    for (int j = 0; j < 4; ++j) { accA[j] = bA; accB[j] = bB; }
    int ih0 = oh * 2 - 1;
    int ib  = ow0 * 2 - 1;
    for (int ci = 0; ci < 64; ++ci) {
        const float* ip = in + ((size_t)(b * 64 + ci) * 128) * 128;
        const float* wA = w + ((size_t)(co0       * 64) + ci) * 16;
        const float* wB = w + ((size_t)((co0 + 64) * 64) + ci) * 16;
        for (int kh = 0; kh < 4; ++kh) {
            int ih = ih0 + kh;
            if ((unsigned)ih >= 128u) continue;
            const float* row = ip + ih * 128;
            float v[10];
            #pragma unroll
            for (int t = 0; t < 10; ++t) {
                int iw = ib + t;
                v[t] = ((unsigned)iw < 128u) ? row[iw] : 0.f;
            }
            #pragma unroll
            for (int kw = 0; kw < 4; ++kw) {
                float a = wA[kh * 4 + kw], c = wB[kh * 4 + kw];
                #pragma unroll
                for (int j = 0; j < 4; ++j) {
                    float xv = v[2 * j + kw];
                    accA[j] = fmaf(xv, a, accA[j]);
                    accB[j] = fmaf(xv, c, accB[j]);
                }
            }
        }
    }
    float* op = out + ((size_t)(b * 128 + co0) * 64 + oh) * 64 + ow0;
    for (int j = 0; j < 4; ++j) op[j] = fmaxf(accA[j], 0.f);
    op += (size_t)64 * 64 * 64;
    for (int j = 0; j < 4; ++j) op[j] = fmaxf(accB[j], 0.f);
}

// conv3: h2(c,128,64,64) -> z(c,64,64,64), k3 s1 p1. Thread = 2co x 4ow.
__global__ __launch_bounds__(256) void conv3_k(
    const float* __restrict__ in, const float* __restrict__ w,
    const float* __restrict__ bias, float* __restrict__ out)
{
    int T = blockIdx.x * 256 + threadIdx.x;     // c * 32,768 threads
    int owq = T & 15;
    int oh  = (T >> 4) & 63;
    int co0 = (T >> 10) & 31;
    int b   = T >> 15;
    int ow0 = owq * 4;
    float accA[4], accB[4];
    float bA = bias[co0], bB = bias[co0 + 32];
    for (int j = 0; j < 4; ++j) { accA[j] = bA; accB[j] = bB; }
    int ib = ow0 - 1;
    for (int ci = 0; ci < 128; ++ci) {
        const float* ip = in + ((size_t)(b * 128 + ci) * 64) * 64;
        const float* wA = w + ((size_t)(co0       * 128) + ci) * 9;
        const float* wB = w + ((size_t)((co0 + 32) * 128) + ci) * 9;
        for (int kh = 0; kh < 3; ++kh) {
            int ih = oh - 1 + kh;
            if ((unsigned)ih >= 64u) continue;
            const float* row = ip + ih * 64;
            float v[6];
            #pragma unroll
            for (int t = 0; t < 6; ++t) {
                int iw = ib + t;
                v[t] = ((unsigned)iw < 64u) ? row[iw] : 0.f;
            }
            #pragma unroll
            for (int kw = 0; kw < 3; ++kw) {
                float a = wA[kh * 3 + kw], c = wB[kh * 3 + kw];
                #pragma unroll
                for (int j = 0; j < 4; ++j) {
                    float xv = v[j + kw];
                    accA[j] = fmaf(xv, a, accA[j]);
                    accB[j] = fmaf(xv, c, accB[j]);
                }
            }
        }
    }
    float* op = out + ((size_t)(b * 64 + co0) * 64 + oh) * 64 + ow0;
    for (int j = 0; j < 4; ++j) op[j] = fmaxf(accA[j], 0.f);
    op += (size_t)32 * 64 * 64;
    for (int j = 0; j < 4; ++j) op[j] = fmaxf(accB[j], 0.f);
}

// VQ: z(c,64,64,64) NCHW -> q(c,64,64,64) NCHW + loss atomic accumulation.
__global__ __launch_bounds__(256) void vq_k(
    const float* __restrict__ z, const float* __restrict__ emb,
    float* __restrict__ q, float* __restrict__ loss_acc)
{
    __shared__ float se2[512];
    __shared__ float red[256];
    int tid = threadIdx.x;
    for (int k = tid; k < 512; k += 256) {
        const float* e = emb + k * 64;
        float s = 0.f;
        for (int d = 0; d < 64; ++d) s = fmaf(e[d], e[d], s);
        se2[k] = s;
    }
    __syncthreads();
    int p = blockIdx.x * 256 + tid;             // c * 4096 positions
    int w = p & 63, h = (p >> 6) & 63, b = p >> 12;
    const float* zp = z + (size_t)b * 262144 + h * 64 + w;
    float zv[64];
    #pragma unroll
    for (int d = 0; d < 64; ++d) zv[d] = zp[(size_t)d * 4096];
    float best = 1e30f;
    int bi = 0;
    for (int k = 0; k < 512; ++k) {
        const float4* e4 = (const float4*)(emb + k * 64);
        float d0 = 0.f, d1 = 0.f, d2 = 0.f, d3 = 0.f;
        #pragma unroll
        for (int t = 0; t < 16; ++t) {
            float4 e = e4[t];
            d0 = fmaf(e.x, zv[4 * t + 0], d0);
            d1 = fmaf(e.y, zv[4 * t + 1], d1);
            d2 = fmaf(e.z, zv[4 * t + 2], d2);
            d3 = fmaf(e.w, zv[4 * t + 3], d3);
        }
        float dot = (d0 + d1) + (d2 + d3);
        float score = fmaf(-2.f, dot, se2[k]);
        if (score < best) { best = score; bi = k; }   // strict < : first-min tie-break
    }
    float lsum = 0.f;
    const float* e = emb + bi * 64;
    float* qp = q + (size_t)b * 262144 + h * 64 + w;
    #pragma unroll
    for (int d = 0; d < 64; ++d) {
        float ev = e[d];
        qp[(size_t)d * 4096] = ev;
        float df = ev - zv[d];
        lsum = fmaf(df, df, lsum);
    }
    red[tid] = lsum;
    __syncthreads();
    for (int s = 128; s > 0; s >>= 1) {
        if (tid < s) red[tid] += red[tid + s];
        __syncthreads();
    }
    if (tid == 0) atomicAdd(loss_acc, red[0]);
}

__global__ void loss_fin_k(const float* __restrict__ acc, float* __restrict__ out)
{
    out[0] = 1.25f * acc[0] / 8388608.0f;
}

// deconv1: q chunk (c,64,64,64) -> d1 (c,128,128,128), k4 s2 p1, relu.
// w layout [Cin=64][Cout=128][4][4]. Thread = 2co x 4ow (same-parity ow).
__global__ __launch_bounds__(256) void deconv1_k(
    const float* __restrict__ in, const float* __restrict__ w,
    const float* __restrict__ bias, float* __restrict__ out)
{
    int T = blockIdx.x * 256 + threadIdx.x;     // c * 262,144 threads
    int p   = T & 1;
    int owq = (T >> 1) & 15;
    int oh  = (T >> 5) & 127;
    int co0 = (T >> 12) & 63;
    int b   = T >> 18;
    int h0 = (oh + 1) & 1;
    int ib = owq * 4 + p - 1;
    float accA[4], accB[4];
    float bA = bias[co0], bB = bias[co0 + 64];
    for (int j = 0; j < 4; ++j) { accA[j] = bA; accB[j] = bB; }
    int q0 = 1 - p;
    for (int ci = 0; ci < 64; ++ci) {
        const float* ip = in + ((size_t)(b * 64 + ci) * 64) * 64;
        const float* wA = w + ((size_t)ci * 128 + co0) * 16;
        const float* wB = w + ((size_t)ci * 128 + co0 + 64) * 16;
        #pragma unroll
        for (int t2 = 0; t2 < 2; ++t2) {
            int kh = h0 + 2 * t2;
            int ih = (oh + 1 - kh) >> 1;
            if ((unsigned)ih >= 64u) continue;
            const float* row = ip + ih * 64;
            float v[5];
            #pragma unroll
            for (int t = 0; t < 5; ++t) {
                int iw = ib + t;
                v[t] = ((unsigned)iw < 64u) ? row[iw] : 0.f;
            }
            float a0 = wA[kh * 4 + q0], a2 = wA[kh * 4 + q0 + 2];
            float c0 = wB[kh * 4 + q0], c2 = wB[kh * 4 + q0 + 2];
            #pragma unroll
            for (int j = 0; j < 4; ++j) {
                accA[j] = fmaf(v[1 + j], a0, accA[j]);
                accA[j] = fmaf(v[j],     a2, accA[j]);
                accB[j] = fmaf(v[1 + j], c0, accB[j]);
                accB[j] = fmaf(v[j],     c2, accB[j]);
            }
        }
    }
    int ow0 = owq * 8 + p;
    float* op = out + (((size_t)b * 128 + co0) * 128 + oh) * 128 + ow0;
    for (int j = 0; j < 4; ++j) op[2 * j] = fmaxf(accA[j], 0.f);
    op += (size_t)64 * 128 * 128;
    for (int j = 0; j < 4; ++j) op[2 * j] = fmaxf(accB[j], 0.f);
}

// deconv2: d1 (c,128,128,128) -> d2 (c,64,256,256), k4 s2 p1, relu.
// w layout [Cin=128][Cout=64][4][4].
__global__ __launch_bounds__(256) void deconv2_k(
    const float* __restrict__ in, const float* __restrict__ w,
    const float* __restrict__ bias, float* __restrict__ out)
{
    int T = blockIdx.x * 256 + threadIdx.x;     // c * 524,288 threads
    int p   = T & 1;
    int owb = (T >> 1) & 31;
    int oh  = (T >> 6) & 255;
    int co0 = (T >> 14) & 31;
    int b   = T >> 19;
    int h0 = (oh + 1) & 1;
    int ib = owb * 4 + p - 1;
    float accA[4], accB[4];
    float bA = bias[co0], bB = bias[co0 + 32];
    for (int j = 0; j < 4; ++j) { accA[j] = bA; accB[j] = bB; }
    int q0 = 1 - p;
    for (int ci = 0; ci < 128; ++ci) {
        const float* ip = in + ((size_t)(b * 128 + ci) * 128) * 128;
        const float* wA = w + ((size_t)ci * 64 + co0) * 16;
        const float* wB = w + ((size_t)ci * 64 + co0 + 32) * 16;
        #pragma unroll
        for (int t2 = 0; t2 < 2; ++t2) {
            int kh = h0 + 2 * t2;
            int ih = (oh + 1 - kh) >> 1;
            if ((unsigned)ih >= 128u) continue;
            const float* row = ip + ih * 128;
            float v[5];
            #pragma unroll
            for (int t = 0; t < 5; ++t) {
                int iw = ib + t;
                v[t] = ((unsigned)iw < 128u) ? row[iw] : 0.f;
            }
            float a0 = wA[kh * 4 + q0], a2 = wA[kh * 4 + q0 + 2];
            float c0 = wB[kh * 4 + q0], c2 = wB[kh * 4 + q0 + 2];
            #pragma unroll
            for (int j = 0; j < 4; ++j) {
                accA[j] = fmaf(v[1 + j], a0, accA[j]);
                accA[j] = fmaf(v[j],     a2, accA[j]);
                accB[j] = fmaf(v[1 + j], c0, accB[j]);
                accB[j] = fmaf(v[j],     c2, accB[j]);
            }
        }
    }
    int ow0 = owb * 8 + p;
    float* op = out + (((size_t)b * 64 + co0) * 256 + oh) * 256 + ow0;
    for (int j = 0; j < 4; ++j) op[2 * j] = fmaxf(accA[j], 0.f);
    op += (size_t)32 * 256 * 256;
    for (int j = 0; j < 4; ++j) op[2 * j] = fmaxf(accB[j], 0.f);
}

// deconv3: d2 (c,64,256,256) -> out slice (c,3,256,256), k3 s1 p1, sigmoid.
// w layout [Cin=64][Cout=3][3][3]. Thread = 4ow.
__global__ __launch_bounds__(256) void deconv3_k(
    const float* __restrict__ in, const float* __restrict__ w,
    const float* __restrict__ bias, float* __restrict__ out)
{
    int T = blockIdx.x * 256 + threadIdx.x;     // c * 49,152 threads
    int owq = T & 63;
    int oh  = (T >> 6) & 255;
    int r   = T >> 14;
    int co  = r % 3;
    int b   = r / 3;
    int ow0 = owq * 4;
    int ib = ow0 - 1;
    float acc[4];
    float bs = bias[co];
    for (int j = 0; j < 4; ++j) acc[j] = bs;
    for (int ci = 0; ci < 64; ++ci) {
        const float* ip = in + ((size_t)(b * 64 + ci) * 256) * 256;
        const float* wp = w + ((size_t)ci * 3 + co) * 9;
        #pragma unroll
        for (int kh = 0; kh < 3; ++kh) {
            int ih = oh + 1 - kh;
            if ((unsigned)ih >= 256u) continue;
            const float* row = ip + ih * 256;
            float v[6];
            #pragma unroll
            for (int t = 0; t < 6; ++t) {
                int iw = ib + t;
                v[t] = ((unsigned)iw < 256u) ? row[iw] : 0.f;
            }
            #pragma unroll
            for (int kw = 0; kw < 3; ++kw) {
                float a = wp[kh * 3 + kw];
                #pragma unroll
                for (int j = 0; j < 4; ++j)
                    acc[j] = fmaf(v[j + 2 - kw], a, acc[j]);
            }
        }
    }
    float* op = out + (((size_t)b * 3 + co) * 256 + oh) * 256 + ow0;
    for (int j = 0; j < 4; ++j)
        op[j] = 1.f / (1.f + __expf(-acc[j]));
}

extern "C" void kernel_launch(void* const* d_in, const int* in_sizes, int n_in,
                              void* d_out, int out_size, void* d_ws, size_t ws_size,
                              hipStream_t stream)
{
    const float* x   = (const float*)d_in[0];
    const float* w1  = (const float*)d_in[1];
    const float* b1  = (const float*)d_in[2];
    const float* w2  = (const float*)d_in[3];
    const float* b2  = (const float*)d_in[4];
    const float* w3  = (const float*)d_in[5];
    const float* b3  = (const float*)d_in[6];
    const float* emb = (const float*)d_in[7];
    const float* dw1 = (const float*)d_in[8];
    const float* db1 = (const float*)d_in[9];
    const float* dw2 = (const float*)d_in[10];
    const float* db2 = (const float*)d_in[11];
    const float* dw3 = (const float*)d_in[12];
    const float* db3 = (const float*)d_in[13];
    float* xout = (float*)d_out;
    float* ws = (float*)d_ws;
    size_t F = ws_size / sizeof(float);   // floats available

    const size_t IMG_X  = 196608;   // 3*256*256
    const size_t IMG_Z  = 262144;   // 64*64*64
    const size_t IMG_O  = 196608;   // 3*256*256

    if (F >= 67108864) {
        // FULL-BATCH path: exactly 256 MiB footprint.
        // h1 [0, 33.55M) -> reused as d2; h2 [33.55M, 50.33M) -> reused as d1;
        // lac lives at h2[0] in the gap between conv3 (last h2 read) and
        // deconv1 (first d1 write); loss_fin consumes it before that.
        float* h1  = ws;
        float* h2  = ws + 33554432;
        float* zb  = ws + 50331648;
        float* qb  = ws + 58720256;
        float* lac = h2;
        float* d1  = h2;
        float* d2  = h1;

        conv1_k<<<131072, 256, 0, stream>>>(x, w1, b1, h1);
        conv2_k<<<8192,   256, 0, stream>>>(h1, w2, b2, h2);
        conv3_k<<<4096,   256, 0, stream>>>(h2, w3, b3, zb);
        zero_k <<<1, 1, 0, stream>>>(lac);
        vq_k   <<<512,    256, 0, stream>>>(zb, emb, qb, lac);
        loss_fin_k<<<1, 1, 0, stream>>>(lac, xout + 6291456);

        for (int c0 = 0; c0 < 32; c0 += 8) {
            deconv1_k<<<8192,  256, 0, stream>>>(qb + (size_t)c0 * IMG_Z, dw1, db1, d1);
            deconv2_k<<<16384, 256, 0, stream>>>(d1, dw2, db2, d2);
            deconv3_k<<<1536,  256, 0, stream>>>(d2, dw3, db3, xout + (size_t)c0 * IMG_O);
        }
    } else {
        // CHUNKED path: process c images end-to-end per iteration.
        // Footprint: c*(4,194,304 + 2,097,152 + 262,144 + 262,144) + 64 floats.
        int c = 8;
        while (c > 1 && F < (size_t)c * 6815744 + 64) c >>= 1;
        float* A   = ws;                            // conv1 out, then d2
        float* B   = A + (size_t)c * 4194304;       // conv2 out, then d1
        float* zc  = B + (size_t)c * 2097152;
        float* qc  = zc + (size_t)c * IMG_Z;
        float* lac = qc + (size_t)c * IMG_Z;

        zero_k<<<1, 1, 0, stream>>>(lac);
        for (int c0 = 0; c0 < 32; c0 += c) {
            conv1_k<<<c * 4096, 256, 0, stream>>>(x + (size_t)c0 * IMG_X, w1, b1, A);
            conv2_k<<<c * 256,  256, 0, stream>>>(A, w2, b2, B);
            conv3_k<<<c * 128,  256, 0, stream>>>(B, w3, b3, zc);
            vq_k   <<<c * 16,   256, 0, stream>>>(zc, emb, qc, lac);
            deconv1_k<<<c * 1024, 256, 0, stream>>>(qc, dw1, db1, B);
            deconv2_k<<<c * 2048, 256, 0, stream>>>(B, dw2, db2, A);
            deconv3_k<<<c * 192,  256, 0, stream>>>(A, dw3, db3, xout + (size_t)c0 * IMG_O);
        }
        loss_fin_k<<<1, 1, 0, stream>>>(lac, xout + 6291456);
    }
}

// Round 4
// 2536.009 us; speedup vs baseline: 5.9788x; 5.9788x over previous
//
#include <hip/hip_runtime.h>
#include <math.h>

// ---------------------------------------------------------------------------
// VQ-VAE forward, round 3: fix d2c under-allocation (8*258*258*64 = 34,080,768,
// was 34,074,624 -> image-7 bottom halo aliased zb's live z values, injecting
// ~0.3 pre-sigmoid garbage at the bottom edge => absmax 0.1).
// bf16 MFMA implicit-GEMM for conv2/conv3/deconv1/deconv2/deconv3 with
// zero-padded NHWC bf16 activations (unconditional 16B A-loads).
// MFMA layouts (learn_hip m89/m120): A/B frag: row=lane&15, k=(lane>>4)*8+j.
// C/D: col(n)=lane&15, row(m)=(lane>>4)*4+reg.
// ---------------------------------------------------------------------------

typedef __attribute__((ext_vector_type(8))) short bf16x8;
typedef __attribute__((ext_vector_type(4))) float fx4;
typedef unsigned short ushort_t;
#define MFMA16(a, b, c) __builtin_amdgcn_mfma_f32_16x16x32_bf16(a, b, c, 0, 0, 0)

__device__ inline ushort_t f2bf(float f) {
    unsigned u = __float_as_uint(f);
    u += 0x7FFFu + ((u >> 16) & 1u);
    return (ushort_t)(u >> 16);
}

__global__ void zero_k(float* __restrict__ p) { p[0] = 0.f; }

// ------------------------- weight repack kernels ---------------------------
// w2 [128co][64ci][4][4] -> Wr2 [co][kh][kw][ci] bf16 (131072)
__global__ __launch_bounds__(256) void repack_w2(const float* __restrict__ w, ushort_t* __restrict__ o) {
    int i = blockIdx.x * 256 + threadIdx.x;
    int ci = i & 63, kw = (i >> 6) & 3, kh = (i >> 8) & 3, co = i >> 10;
    o[i] = f2bf(w[((co * 64 + ci) * 4 + kh) * 4 + kw]);
}
// w3 [64co][128ci][3][3] -> Wr3 [co][tap9][ci] bf16 (73728)
__global__ __launch_bounds__(256) void repack_w3(const float* __restrict__ w, ushort_t* __restrict__ o) {
    int i = blockIdx.x * 256 + threadIdx.x;
    if (i >= 73728) return;
    int ci = i & 127, t = (i >> 7) % 9, co = i / 1152;
    int kh = t / 3, kw = t % 3;
    o[i] = f2bf(w[((co * 128 + ci) * 3 + kh) * 3 + kw]);
}
// dw1 [64ci][128co][4][4] -> Wd1 [co][kh][kw][ci] bf16 (131072), NO flip (gather form)
__global__ __launch_bounds__(256) void repack_d1(const float* __restrict__ w, ushort_t* __restrict__ o) {
    int i = blockIdx.x * 256 + threadIdx.x;
    int ci = i & 63, kw = (i >> 6) & 3, kh = (i >> 8) & 3, co = i >> 10;
    o[i] = f2bf(w[((ci * 128 + co) * 4 + kh) * 4 + kw]);
}
// dw2 [128ci][64co][4][4] -> Wd2 [co][kh][kw][ci] bf16 (131072)
__global__ __launch_bounds__(256) void repack_d2(const float* __restrict__ w, ushort_t* __restrict__ o) {
    int i = blockIdx.x * 256 + threadIdx.x;
    int ci = i & 127, kw = (i >> 7) & 3, kh = (i >> 9) & 3, co = i >> 11;
    o[i] = f2bf(w[((ci * 64 + co) * 4 + kh) * 4 + kw]);
}
// dw3 [64ci][3co][3][3] -> Wd3 [co16][tap9][ci64] bf16 (9216), co>=3 zero
__global__ __launch_bounds__(256) void repack_d3(const float* __restrict__ w, ushort_t* __restrict__ o) {
    int i = blockIdx.x * 256 + threadIdx.x;
    if (i >= 9216) return;
    int ci = i & 63, t = (i >> 6) % 9, co = i / 576;
    int kh = t / 3, kw = t % 3;
    o[i] = (co < 3) ? f2bf(w[((ci * 3 + co) * 3 + kh) * 3 + kw]) : (ushort_t)0;
}

// ------------------------- conv1 (fp32 -> padded NHWC bf16) ----------------
// x(32,3,256,256) f32 -> x_p[32][130][130][64] bf16. k4 s2 p1 relu.
// lane = co (64), wave handles 4 ow pixels; x loads wave-uniform (broadcast).
__global__ __launch_bounds__(256) void conv1_k(
    const float* __restrict__ x, const float* __restrict__ w,
    const float* __restrict__ bias, ushort_t* __restrict__ xp)
{
    int wave = threadIdx.x >> 6;
    int lane = threadIdx.x & 63;            // co
    int blk = blockIdx.x;                   // 32*128*8
    int strip = blk & 7;
    int oh = (blk >> 3) & 127;
    int b = blk >> 10;
    int owb = strip * 16 + wave * 4;
    float wr[48];
    const float* wp = w + lane * 48;        // [co][ci][kh][kw]
    #pragma unroll
    for (int i = 0; i < 48; ++i) wr[i] = wp[i];
    float acc[4];
    float bs = bias[lane];
    #pragma unroll
    for (int j = 0; j < 4; ++j) acc[j] = bs;
    int ib = owb * 2 - 1;
    for (int ci = 0; ci < 3; ++ci) {
        const float* plane = x + ((size_t)(b * 3 + ci) * 256) * 256;
        #pragma unroll
        for (int kh = 0; kh < 4; ++kh) {
            int ih = oh * 2 - 1 + kh;
            if ((unsigned)ih >= 256u) continue;
            const float* row = plane + ih * 256;
            float v[10];
            #pragma unroll
            for (int t = 0; t < 10; ++t) {
                int iw = ib + t;
                v[t] = ((unsigned)iw < 256u) ? row[iw] : 0.f;
            }
            #pragma unroll
            for (int kw = 0; kw < 4; ++kw) {
                float wv = wr[ci * 16 + kh * 4 + kw];
                #pragma unroll
                for (int j = 0; j < 4; ++j) acc[j] = fmaf(v[2 * j + kw], wv, acc[j]);
            }
        }
    }
    #pragma unroll
    for (int j = 0; j < 4; ++j) {
        size_t a = ((size_t)(b * 130 + oh + 1) * 130 + (owb + j + 1)) * 64 + lane;
        xp[a] = f2bf(fmaxf(acc[j], 0.f));
    }
}

// ------------------------- conv2 MFMA --------------------------------------
// x_p[32][130][130][64] -> h2p[32][66][66][128]. k4 s2 p1 relu.
// Block=(b,oh): M=64(ow) x N=128. Wave: cobase=wv*32, 4 mt x 2 nt.
__global__ __launch_bounds__(256) void conv2_mfma(
    const ushort_t* __restrict__ xp, const ushort_t* __restrict__ wr,
    const float* __restrict__ bias, ushort_t* __restrict__ h2p)
{
    int wv = threadIdx.x >> 6;
    int lane = threadIdx.x & 63;
    int n16 = lane & 15, quad = lane >> 4;
    int blk = blockIdx.x;                   // 32*64
    int oh = blk & 63, b = blk >> 6;
    const ushort_t* xb = xp + (size_t)b * 130 * 130 * 64;
    int cobase = wv * 32;
    fx4 acc[4][2];
    #pragma unroll
    for (int i = 0; i < 4; ++i)
        #pragma unroll
        for (int j = 0; j < 2; ++j) acc[i][j] = (fx4){0.f, 0.f, 0.f, 0.f};
    for (int tap = 0; tap < 16; ++tap) {
        int kh = tap >> 2, kw = tap & 3;
        const ushort_t* arow = xb + ((size_t)(2 * oh + kh) * 130 + kw) * 64 + quad * 8;
        const ushort_t* brow = wr + (size_t)tap * 64 + quad * 8;
        #pragma unroll
        for (int ks = 0; ks < 2; ++ks) {
            bf16x8 af[4], bfr[2];
            #pragma unroll
            for (int mt = 0; mt < 4; ++mt)
                af[mt] = *(const bf16x8*)(arow + (size_t)(2 * (mt * 16 + n16)) * 64 + ks * 32);
            #pragma unroll
            for (int nt = 0; nt < 2; ++nt)
                bfr[nt] = *(const bf16x8*)(brow + (size_t)(cobase + nt * 16 + n16) * 1024 + ks * 32);
            #pragma unroll
            for (int mt = 0; mt < 4; ++mt)
                #pragma unroll
                for (int nt = 0; nt < 2; ++nt)
                    acc[mt][nt] = MFMA16(af[mt], bfr[nt], acc[mt][nt]);
        }
    }
    #pragma unroll
    for (int nt = 0; nt < 2; ++nt) {
        int co = cobase + nt * 16 + n16;
        float bs = bias[co];
        #pragma unroll
        for (int mt = 0; mt < 4; ++mt) {
            #pragma unroll
            for (int r = 0; r < 4; ++r) {
                int ow = mt * 16 + quad * 4 + r;
                float v = fmaxf(acc[mt][nt][r] + bs, 0.f);
                h2p[((size_t)(b * 66 + oh + 1) * 66 + (ow + 1)) * 128 + co] = f2bf(v);
            }
        }
    }
}

// ------------------------- conv3 MFMA --------------------------------------
// h2p[32][66][66][128] -> z[32][64][64][64] (unpadded NHWC). k3 s1 p1 relu.
// Block=(b,oh): M=64 x N=64. Wave: cobase=wv*16, 4 mt x 1 nt.
__global__ __launch_bounds__(256) void conv3_mfma(
    const ushort_t* __restrict__ hp, const ushort_t* __restrict__ wr,
    const float* __restrict__ bias, ushort_t* __restrict__ z)
{
    int wv = threadIdx.x >> 6;
    int lane = threadIdx.x & 63;
    int n16 = lane & 15, quad = lane >> 4;
    int blk = blockIdx.x;                   // 32*64
    int oh = blk & 63, b = blk >> 6;
    const ushort_t* hb = hp + (size_t)b * 66 * 66 * 128;
    int co = wv * 16 + n16;
    fx4 acc[4];
    #pragma unroll
    for (int i = 0; i < 4; ++i) acc[i] = (fx4){0.f, 0.f, 0.f, 0.f};
    for (int tap = 0; tap < 9; ++tap) {
        int kh = tap / 3, kw = tap % 3;
        const ushort_t* arow = hb + ((size_t)(oh + kh) * 66 + kw) * 128 + quad * 8;
        const ushort_t* brow = wr + (size_t)co * 1152 + tap * 128 + quad * 8;
        #pragma unroll
        for (int ks = 0; ks < 4; ++ks) {
            bf16x8 af[4];
            #pragma unroll
            for (int mt = 0; mt < 4; ++mt)
                af[mt] = *(const bf16x8*)(arow + (size_t)(mt * 16 + n16) * 128 + ks * 32);
            bf16x8 bfr = *(const bf16x8*)(brow + ks * 32);
            #pragma unroll
            for (int mt = 0; mt < 4; ++mt)
                acc[mt] = MFMA16(af[mt], bfr, acc[mt]);
        }
    }
    float bs = bias[co];
    #pragma unroll
    for (int mt = 0; mt < 4; ++mt) {
        #pragma unroll
        for (int r = 0; r < 4; ++r) {
            int ow = mt * 16 + quad * 4 + r;
            float v = fmaxf(acc[mt][r] + bs, 0.f);
            z[((size_t)(b * 64 + oh) * 64 + ow) * 64 + co] = f2bf(v);
        }
    }
}

// ------------------------- VQ ----------------------------------------------
// z NHWC bf16 -> q_pad[32][66][66][64] bf16 + loss (fp32 math, fp32 emb).
__global__ __launch_bounds__(256) void vq_k(
    const ushort_t* __restrict__ z, const float* __restrict__ emb,
    ushort_t* __restrict__ qpad, float* __restrict__ loss_acc)
{
    __shared__ float se2[512];
    __shared__ float red[256];
    int tid = threadIdx.x;
    for (int k = tid; k < 512; k += 256) {
        const float* e = emb + k * 64;
        float s = 0.f;
        for (int d = 0; d < 64; ++d) s = fmaf(e[d], e[d], s);
        se2[k] = s;
    }
    __syncthreads();
    int p = blockIdx.x * 256 + tid;         // 131072 positions
    int wc = p & 63, h = (p >> 6) & 63, b = p >> 12;
    const unsigned* zr = (const unsigned*)(z + (size_t)p * 64);
    float zv[64];
    #pragma unroll
    for (int t = 0; t < 32; ++t) {
        unsigned u = zr[t];
        zv[2 * t]     = __uint_as_float(u << 16);
        zv[2 * t + 1] = __uint_as_float(u & 0xFFFF0000u);
    }
    float best = 1e30f;
    int bi = 0;
    for (int k = 0; k < 512; ++k) {
        const float4* e4 = (const float4*)(emb + k * 64);
        float d0 = 0.f, d1 = 0.f, d2 = 0.f, d3 = 0.f;
        #pragma unroll
        for (int t = 0; t < 16; ++t) {
            float4 e = e4[t];
            d0 = fmaf(e.x, zv[4 * t + 0], d0);
            d1 = fmaf(e.y, zv[4 * t + 1], d1);
            d2 = fmaf(e.z, zv[4 * t + 2], d2);
            d3 = fmaf(e.w, zv[4 * t + 3], d3);
        }
        float dot = (d0 + d1) + (d2 + d3);
        float score = fmaf(-2.f, dot, se2[k]);
        if (score < best) { best = score; bi = k; }  // first-min tie-break
    }
    float lsum = 0.f;
    const float* e = emb + bi * 64;
    unsigned* qp = (unsigned*)(qpad + ((size_t)(b * 66 + h + 1) * 66 + (wc + 1)) * 64);
    #pragma unroll
    for (int t = 0; t < 32; ++t) {
        float e0 = e[2 * t], e1 = e[2 * t + 1];
        float f0 = e0 - zv[2 * t], f1 = e1 - zv[2 * t + 1];
        lsum = fmaf(f0, f0, lsum);
        lsum = fmaf(f1, f1, lsum);
        qp[t] = (unsigned)f2bf(e0) | ((unsigned)f2bf(e1) << 16);
    }
    red[tid] = lsum;
    __syncthreads();
    for (int s = 128; s > 0; s >>= 1) {
        if (tid < s) red[tid] += red[tid + s];
        __syncthreads();
    }
    if (tid == 0) atomicAdd(loss_acc, red[0]);
}

__global__ void loss_fin_k(const float* __restrict__ acc, float* __restrict__ out)
{
    out[0] = 1.25f * acc[0] / 8388608.0f;
}

// ------------------------- deconv1 MFMA ------------------------------------
// q_pad chunk [8][66][66][64] -> d1c[8][130][130][128]. k4 s2 p1 relu, gather.
// Block=(b,oh,p): M=64 (ow=2t+p) x N=128. Wave: cobase=wv*32, 4mt x 2nt.
__global__ __launch_bounds__(256) void deconv1_mfma(
    const ushort_t* __restrict__ q, const ushort_t* __restrict__ wr,
    const float* __restrict__ bias, ushort_t* __restrict__ d1)
{
    int wv = threadIdx.x >> 6;
    int lane = threadIdx.x & 63;
    int n16 = lane & 15, quad = lane >> 4;
    int blk = blockIdx.x;                   // 8*128*2
    int pp = blk & 1;
    int oh = (blk >> 1) & 127;
    int b = blk >> 8;
    int h0 = (oh + 1) & 1, q0 = 1 - pp;
    const ushort_t* qb = q + (size_t)b * 66 * 66 * 64;
    int cobase = wv * 32;
    fx4 acc[4][2];
    #pragma unroll
    for (int i = 0; i < 4; ++i)
        #pragma unroll
        for (int j = 0; j < 2; ++j) acc[i][j] = (fx4){0.f, 0.f, 0.f, 0.f};
    #pragma unroll
    for (int t2 = 0; t2 < 2; ++t2) {
        int kh = h0 + 2 * t2;
        int ihp = ((oh + 1 - kh) >> 1) + 1;     // 0..65 (halo rows are zero)
        #pragma unroll
        for (int t3 = 0; t3 < 2; ++t3) {
            int kw = q0 + 2 * t3;
            int coladd = pp + (t3 == 0 ? 1 : 0);
            int tapi = kh * 4 + kw;
            const ushort_t* arow = qb + ((size_t)ihp * 66 + coladd) * 64 + quad * 8;
            const ushort_t* brow = wr + (size_t)tapi * 64 + quad * 8;
            #pragma unroll
            for (int ks = 0; ks < 2; ++ks) {
                bf16x8 af[4], bfr[2];
                #pragma unroll
                for (int mt = 0; mt < 4; ++mt)
                    af[mt] = *(const bf16x8*)(arow + (size_t)(mt * 16 + n16) * 64 + ks * 32);
                #pragma unroll
                for (int nt = 0; nt < 2; ++nt)
                    bfr[nt] = *(const bf16x8*)(brow + (size_t)(cobase + nt * 16 + n16) * 1024 + ks * 32);
                #pragma unroll
                for (int mt = 0; mt < 4; ++mt)
                    #pragma unroll
                    for (int nt = 0; nt < 2; ++nt)
                        acc[mt][nt] = MFMA16(af[mt], bfr[nt], acc[mt][nt]);
            }
        }
    }
    #pragma unroll
    for (int nt = 0; nt < 2; ++nt) {
        int co = cobase + nt * 16 + n16;
        float bs = bias[co];
        #pragma unroll
        for (int mt = 0; mt < 4; ++mt) {
            #pragma unroll
            for (int r = 0; r < 4; ++r) {
                int ow = 2 * (mt * 16 + quad * 4 + r) + pp;
                float v = fmaxf(acc[mt][nt][r] + bs, 0.f);
                d1[((size_t)(b * 130 + oh + 1) * 130 + (ow + 1)) * 128 + co] = f2bf(v);
            }
        }
    }
}

// ------------------------- deconv2 MFMA ------------------------------------
// d1c[8][130][130][128] -> d2c[8][258][258][64]. k4 s2 p1 relu, gather.
// Block=(b,oh,p,half): M=64 (t=half*64+..) x N=64. Wave: co=wv*16, 4mt.
__global__ __launch_bounds__(256) void deconv2_mfma(
    const ushort_t* __restrict__ d1, const ushort_t* __restrict__ wr,
    const float* __restrict__ bias, ushort_t* __restrict__ d2)
{
    int wv = threadIdx.x >> 6;
    int lane = threadIdx.x & 63;
    int n16 = lane & 15, quad = lane >> 4;
    int blk = blockIdx.x;                   // 8*256*2*2
    int half = blk & 1;
    int pp = (blk >> 1) & 1;
    int oh = (blk >> 2) & 255;
    int b = blk >> 10;
    int h0 = (oh + 1) & 1, q0 = 1 - pp;
    int tbase = half * 64;
    const ushort_t* db = d1 + (size_t)b * 130 * 130 * 128;
    int co = wv * 16 + n16;
    fx4 acc[4];
    #pragma unroll
    for (int i = 0; i < 4; ++i) acc[i] = (fx4){0.f, 0.f, 0.f, 0.f};
    #pragma unroll
    for (int t2 = 0; t2 < 2; ++t2) {
        int kh = h0 + 2 * t2;
        int ihp = ((oh + 1 - kh) >> 1) + 1;     // 0..129 (halo rows zero)
        #pragma unroll
        for (int t3 = 0; t3 < 2; ++t3) {
            int kw = q0 + 2 * t3;
            int coladd = tbase + pp + (t3 == 0 ? 1 : 0);
            int tapi = kh * 4 + kw;
            const ushort_t* arow = db + ((size_t)ihp * 130 + coladd) * 128 + quad * 8;
            const ushort_t* brow = wr + (size_t)co * 2048 + tapi * 128 + quad * 8;
            #pragma unroll
            for (int ks = 0; ks < 4; ++ks) {
                bf16x8 af[4];
                #pragma unroll
                for (int mt = 0; mt < 4; ++mt)
                    af[mt] = *(const bf16x8*)(arow + (size_t)(mt * 16 + n16) * 128 + ks * 32);
                bf16x8 bfr = *(const bf16x8*)(brow + ks * 32);
                #pragma unroll
                for (int mt = 0; mt < 4; ++mt)
                    acc[mt] = MFMA16(af[mt], bfr, acc[mt]);
            }
        }
    }
    float bs = bias[co];
    #pragma unroll
    for (int mt = 0; mt < 4; ++mt) {
        #pragma unroll
        for (int r = 0; r < 4; ++r) {
            int ow = 2 * (tbase + mt * 16 + quad * 4 + r) + pp;
            float v = fmaxf(acc[mt][r] + bs, 0.f);
            d2[((size_t)(b * 258 + oh + 1) * 258 + (ow + 1)) * 64 + co] = f2bf(v);
        }
    }
}

// ------------------------- deconv3 MFMA ------------------------------------
// d2c[8][258][258][64] -> out chunk (8,3,256,256) f32 NCHW, sigmoid. k3 s1 p1.
// Block=(b,oh): M=256 x N=16(3 used). Wave: mt=wv*4+i.
__global__ __launch_bounds__(256) void deconv3_mfma(
    const ushort_t* __restrict__ d2, const ushort_t* __restrict__ wr,
    const float* __restrict__ bias, float* __restrict__ out)
{
    int wv = threadIdx.x >> 6;
    int lane = threadIdx.x & 63;
    int n16 = lane & 15, quad = lane >> 4;
    int blk = blockIdx.x;                   // 8*256
    int oh = blk & 255, b = blk >> 8;
    const ushort_t* db = d2 + (size_t)b * 258 * 258 * 64;
    fx4 acc[4];
    #pragma unroll
    for (int i = 0; i < 4; ++i) acc[i] = (fx4){0.f, 0.f, 0.f, 0.f};
    for (int tap = 0; tap < 9; ++tap) {
        int kh = tap / 3, kw = tap % 3;
        const ushort_t* arow = db + ((size_t)(oh + 2 - kh) * 258 + (2 - kw)) * 64 + quad * 8;
        const ushort_t* brow = wr + (size_t)n16 * 576 + tap * 64 + quad * 8;
        #pragma unroll
        for (int ks = 0; ks < 2; ++ks) {
            bf16x8 af[4];
            #pragma unroll
            for (int i = 0; i < 4; ++i) {
                int mt = wv * 4 + i;
                af[i] = *(const bf16x8*)(arow + (size_t)(mt * 16 + n16) * 64 + ks * 32);
            }
            bf16x8 bfr = *(const bf16x8*)(brow + ks * 32);
            #pragma unroll
            for (int i = 0; i < 4; ++i)
                acc[i] = MFMA16(af[i], bfr, acc[i]);
        }
    }
    int co = n16;
    if (co < 3) {
        float bs = bias[co];
        #pragma unroll
        for (int i = 0; i < 4; ++i) {
            int mt = wv * 4 + i;
            int ow0 = mt * 16 + quad * 4;
            float4 v;
            v.x = 1.f / (1.f + __expf(-(acc[i][0] + bs)));
            v.y = 1.f / (1.f + __expf(-(acc[i][1] + bs)));
            v.z = 1.f / (1.f + __expf(-(acc[i][2] + bs)));
            v.w = 1.f / (1.f + __expf(-(acc[i][3] + bs)));
            *(float4*)(out + (((size_t)b * 3 + co) * 256 + oh) * 256 + ow0) = v;
        }
    }
}

// ---------------------------------------------------------------------------
extern "C" void kernel_launch(void* const* d_in, const int* in_sizes, int n_in,
                              void* d_out, int out_size, void* d_ws, size_t ws_size,
                              hipStream_t stream)
{
    const float* x   = (const float*)d_in[0];
    const float* w1  = (const float*)d_in[1];
    const float* b1  = (const float*)d_in[2];
    const float* w2  = (const float*)d_in[3];
    const float* b2  = (const float*)d_in[4];
    const float* w3  = (const float*)d_in[5];
    const float* b3  = (const float*)d_in[6];
    const float* emb = (const float*)d_in[7];
    const float* dw1 = (const float*)d_in[8];
    const float* db1 = (const float*)d_in[9];
    const float* dw2 = (const float*)d_in[10];
    const float* db2 = (const float*)d_in[11];
    const float* dw3 = (const float*)d_in[12];
    const float* db3 = (const float*)d_in[13];
    float* xout = (float*)d_out;

    // workspace carve-up (elements of ushort/bf16)
    ushort_t* xp   = (ushort_t*)d_ws;            // 32*130*130*64 = 34,611,200
    ushort_t* h2p  = xp   + 34611200;            // 32*66*66*128  = 17,842,176
    ushort_t* qpad = h2p  + 17842176;            // 32*66*66*64   =  8,921,088
    ushort_t* d1c  = qpad + 8921088;             //  8*130*130*128= 17,305,600
    ushort_t* d2c  = d1c  + 17305600;            //  8*258*258*64 = 34,080,768
    ushort_t* zb   = d2c  + 34080768;            // 32*64*64*64   =  8,388,608
    ushort_t* wr2  = zb   + 8388608;             // 131,072
    ushort_t* wr3  = wr2  + 131072;              //  73,728
    ushort_t* wd1  = wr3  + 73728;               // 131,072
    ushort_t* wd2  = wd1  + 131072;              // 131,072
    ushort_t* wd3  = wd2  + 131072;              //   9,216
    float*    lac  = (float*)(wd3 + 9216);

    // zero all padded activation buffers (halos must be 0 every call):
    // covers xp..d2c inclusive = 112,760,832 elements = 225,521,664 bytes.
    hipMemsetAsync(d_ws, 0, 225521664ULL, stream);
    zero_k<<<1, 1, 0, stream>>>(lac);

    repack_w2<<<512, 256, 0, stream>>>(w2, wr2);
    repack_w3<<<288, 256, 0, stream>>>(w3, wr3);
    repack_d1<<<512, 256, 0, stream>>>(dw1, wd1);
    repack_d2<<<512, 256, 0, stream>>>(dw2, wd2);
    repack_d3<<<36,  256, 0, stream>>>(dw3, wd3);

    conv1_k   <<<32768, 256, 0, stream>>>(x, w1, b1, xp);
    conv2_mfma<<<2048,  256, 0, stream>>>(xp, wr2, b2, h2p);
    conv3_mfma<<<2048,  256, 0, stream>>>(h2p, wr3, b3, zb);
    vq_k      <<<512,   256, 0, stream>>>(zb, emb, qpad, lac);
    loss_fin_k<<<1, 1, 0, stream>>>(lac, xout + 6291456);

    for (int c0 = 0; c0 < 32; c0 += 8) {
        deconv1_mfma<<<2048, 256, 0, stream>>>(qpad + (size_t)c0 * 278784, wd1, db1, d1c);
        deconv2_mfma<<<8192, 256, 0, stream>>>(d1c, wd2, db2, d2c);
        deconv3_mfma<<<2048, 256, 0, stream>>>(d2c, wd3, db3, xout + (size_t)c0 * 196608);
    }
}

// Round 5
// 1499.787 us; speedup vs baseline: 10.1096x; 1.6909x over previous
//
#include <hip/hip_runtime.h>
#include <math.h>

// ---------------------------------------------------------------------------
// VQ-VAE forward, round 4: LDS-staged MFMA macro-blocks.
// Round-3 problem: MFMA operands fed directly from global -> ~3 loads in
// flight -> latency-bound (MfmaUtil 4.7%). Fix: per block, stage the 2-4
// CONTIGUOUS input rows it needs into LDS via async global_load_lds (flat
// copy, wave-uniform dest), then run 128-256 MFMAs/wave from LDS.
// All index math identical to the round-3 verified kernels.
// MFMA 16x16x32 layouts (m89): A/B frag row=lane&15, k=(lane>>4)*8+j.
// C/D: col(n)=lane&15, row(m)=(lane>>4)*4+reg.
// ---------------------------------------------------------------------------

typedef __attribute__((ext_vector_type(8))) short bf16x8;
typedef __attribute__((ext_vector_type(4))) float fx4;
typedef unsigned short ushort_t;
#define MFMA16(a, b, c) __builtin_amdgcn_mfma_f32_16x16x32_bf16(a, b, c, 0, 0, 0)

__device__ inline ushort_t f2bf(float f) {
    unsigned u = __float_as_uint(f);
    u += 0x7FFFu + ((u >> 16) & 1u);
    return (ushort_t)(u >> 16);
}

// async global->LDS 16B per lane: g is per-lane (base + lane*16B), l is
// wave-uniform; HW scatters lane i to l + i*16.
__device__ __forceinline__ void stage16(const ushort_t* g, ushort_t* l) {
#if __has_builtin(__builtin_amdgcn_global_load_lds)
    __builtin_amdgcn_global_load_lds(
        (const __attribute__((address_space(1))) unsigned int*)g,
        (__attribute__((address_space(3))) unsigned int*)l, 16, 0, 0);
#else
    int lane = threadIdx.x & 63;
    *(int4*)(l + lane * 8) = *(const int4*)g;
#endif
}

__global__ void zero_k(float* __restrict__ p) { p[0] = 0.f; }

// zero halo (rows 0,H-1; cols 0,W-1) of [B][H][W][C8*8] bf16 buffer
__global__ __launch_bounds__(256) void halo_zero(
    ushort_t* __restrict__ buf, int B, int H, int W, int C8)
{
    int idx = blockIdx.x * 256 + threadIdx.x;
    int perim = 2 * W + 2 * (H - 2);
    if (idx >= B * perim * C8) return;
    int c8 = idx % C8;
    int t = idx / C8;
    int p = t % perim;
    int b = t / perim;
    int r, col;
    if (p < W) { r = 0; col = p; }
    else if (p < 2 * W) { r = H - 1; col = p - W; }
    else { int pp = p - 2 * W; r = 1 + (pp >> 1); col = (pp & 1) ? (W - 1) : 0; }
    size_t off = ((((size_t)b * H + r) * W + col) * C8 + c8) * 8;
    *(int4*)(buf + off) = (int4){0, 0, 0, 0};
}

// ------------------------- weight repack kernels ---------------------------
__global__ __launch_bounds__(256) void repack_w2(const float* __restrict__ w, ushort_t* __restrict__ o) {
    int i = blockIdx.x * 256 + threadIdx.x;
    int ci = i & 63, kw = (i >> 6) & 3, kh = (i >> 8) & 3, co = i >> 10;
    o[i] = f2bf(w[((co * 64 + ci) * 4 + kh) * 4 + kw]);
}
__global__ __launch_bounds__(256) void repack_w3(const float* __restrict__ w, ushort_t* __restrict__ o) {
    int i = blockIdx.x * 256 + threadIdx.x;
    if (i >= 73728) return;
    int ci = i & 127, t = (i >> 7) % 9, co = i / 1152;
    int kh = t / 3, kw = t % 3;
    o[i] = f2bf(w[((co * 128 + ci) * 3 + kh) * 3 + kw]);
}
__global__ __launch_bounds__(256) void repack_d1(const float* __restrict__ w, ushort_t* __restrict__ o) {
    int i = blockIdx.x * 256 + threadIdx.x;
    int ci = i & 63, kw = (i >> 6) & 3, kh = (i >> 8) & 3, co = i >> 10;
    o[i] = f2bf(w[((ci * 128 + co) * 4 + kh) * 4 + kw]);
}
__global__ __launch_bounds__(256) void repack_d2(const float* __restrict__ w, ushort_t* __restrict__ o) {
    int i = blockIdx.x * 256 + threadIdx.x;
    int ci = i & 127, kw = (i >> 7) & 3, kh = (i >> 9) & 3, co = i >> 11;
    o[i] = f2bf(w[((ci * 64 + co) * 4 + kh) * 4 + kw]);
}
__global__ __launch_bounds__(256) void repack_d3(const float* __restrict__ w, ushort_t* __restrict__ o) {
    int i = blockIdx.x * 256 + threadIdx.x;
    if (i >= 9216) return;
    int ci = i & 63, t = (i >> 6) % 9, co = i / 576;
    int kh = t / 3, kw = t % 3;
    o[i] = (co < 3) ? f2bf(w[((ci * 3 + co) * 3 + kh) * 3 + kw]) : (ushort_t)0;
}

// ------------------------- conv1 (fp32 -> padded NHWC bf16) ----------------
__global__ __launch_bounds__(256) void conv1_k(
    const float* __restrict__ x, const float* __restrict__ w,
    const float* __restrict__ bias, ushort_t* __restrict__ xp)
{
    int wave = threadIdx.x >> 6;
    int lane = threadIdx.x & 63;            // co
    int blk = blockIdx.x;                   // 32*128*8
    int strip = blk & 7;
    int oh = (blk >> 3) & 127;
    int b = blk >> 10;
    int owb = strip * 16 + wave * 4;
    float wr[48];
    const float* wp = w + lane * 48;
    #pragma unroll
    for (int i = 0; i < 48; ++i) wr[i] = wp[i];
    float acc[4];
    float bs = bias[lane];
    #pragma unroll
    for (int j = 0; j < 4; ++j) acc[j] = bs;
    int ib = owb * 2 - 1;
    for (int ci = 0; ci < 3; ++ci) {
        const float* plane = x + ((size_t)(b * 3 + ci) * 256) * 256;
        #pragma unroll
        for (int kh = 0; kh < 4; ++kh) {
            int ih = oh * 2 - 1 + kh;
            if ((unsigned)ih >= 256u) continue;
            const float* row = plane + ih * 256;
            float v[10];
            #pragma unroll
            for (int t = 0; t < 10; ++t) {
                int iw = ib + t;
                v[t] = ((unsigned)iw < 256u) ? row[iw] : 0.f;
            }
            #pragma unroll
            for (int kw = 0; kw < 4; ++kw) {
                float wv = wr[ci * 16 + kh * 4 + kw];
                #pragma unroll
                for (int j = 0; j < 4; ++j) acc[j] = fmaf(v[2 * j + kw], wv, acc[j]);
            }
        }
    }
    #pragma unroll
    for (int j = 0; j < 4; ++j) {
        size_t a = ((size_t)(b * 130 + oh + 1) * 130 + (owb + j + 1)) * 64 + lane;
        xp[a] = f2bf(fmaxf(acc[j], 0.f));
    }
}

// ------------------------- conv2 MFMA (LDS-staged) -------------------------
// x_p[32][130][130][64] -> h2p[32][66][66][128]. Block=(b,oh): stage rows
// 2oh..2oh+3 (66560B). M=64 x N=128, K=1024. Wave: 2mt x 4nt.
__global__ __launch_bounds__(256) void conv2_mfma(
    const ushort_t* __restrict__ xp, const ushort_t* __restrict__ wr,
    const float* __restrict__ bias, ushort_t* __restrict__ h2p)
{
    __shared__ ushort_t sm[33280];          // 4 x 130 x 64
    int tid = threadIdx.x;
    int wv = tid >> 6, lane = tid & 63;
    int n16 = lane & 15, quad = lane >> 4;
    int blk = blockIdx.x;                   // 2048
    int oh = blk & 63, b = blk >> 6;
    const ushort_t* gsrc = xp + (size_t)(b * 130 + 2 * oh) * 130 * 64;
    for (int u = wv; u < 65; u += 4)
        stage16(gsrc + (size_t)u * 512 + lane * 8, sm + u * 512);
    __syncthreads();

    int mg = wv & 1, ng = wv >> 1;          // mts {mg*2,mg*2+1}, nts {ng*4..+3}
    fx4 acc[2][4];
    #pragma unroll
    for (int i = 0; i < 2; ++i)
        #pragma unroll
        for (int j = 0; j < 4; ++j) acc[i][j] = (fx4){0.f, 0.f, 0.f, 0.f};
    for (int tap = 0; tap < 16; ++tap) {
        int kh = tap >> 2, kw = tap & 3;
        #pragma unroll
        for (int ks = 0; ks < 2; ++ks) {
            bf16x8 bfr[4], af[2];
            #pragma unroll
            for (int nt = 0; nt < 4; ++nt)
                bfr[nt] = *(const bf16x8*)(wr + (size_t)((ng * 4 + nt) * 16 + n16) * 1024 + tap * 64 + ks * 32 + quad * 8);
            #pragma unroll
            for (int mt = 0; mt < 2; ++mt) {
                int px = kw + 2 * ((mg * 2 + mt) * 16 + n16);      // 0..129
                af[mt] = *(const bf16x8*)(sm + (kh * 130 + px) * 64 + ks * 32 + quad * 8);
            }
            #pragma unroll
            for (int mt = 0; mt < 2; ++mt)
                #pragma unroll
                for (int nt = 0; nt < 4; ++nt)
                    acc[mt][nt] = MFMA16(af[mt], bfr[nt], acc[mt][nt]);
        }
    }
    #pragma unroll
    for (int nt = 0; nt < 4; ++nt) {
        int co = (ng * 4 + nt) * 16 + n16;
        float bs = bias[co];
        #pragma unroll
        for (int mt = 0; mt < 2; ++mt) {
            #pragma unroll
            for (int r = 0; r < 4; ++r) {
                int ow = (mg * 2 + mt) * 16 + quad * 4 + r;
                h2p[((size_t)(b * 66 + oh + 1) * 66 + (ow + 1)) * 128 + co] =
                    f2bf(fmaxf(acc[mt][nt][r] + bs, 0.f));
            }
        }
    }
}

// ------------------------- conv3 MFMA (LDS-staged) -------------------------
// h2p -> z[32][64][64][64] unpadded NHWC. Block=(b,oh): stage rows oh..oh+2
// (50688B, stage 50 chunks). M=64 x N=64, K=1152. Wave: 2mt x 2nt.
__global__ __launch_bounds__(256) void conv3_mfma(
    const ushort_t* __restrict__ hp, const ushort_t* __restrict__ wr,
    const float* __restrict__ bias, ushort_t* __restrict__ z)
{
    __shared__ ushort_t sm[25600];          // 3 x 66 x 128 (+tail pad)
    int tid = threadIdx.x;
    int wv = tid >> 6, lane = tid & 63;
    int n16 = lane & 15, quad = lane >> 4;
    int blk = blockIdx.x;                   // 2048
    int oh = blk & 63, b = blk >> 6;
    const ushort_t* gsrc = hp + (size_t)(b * 66 + oh) * 66 * 128;
    for (int u = wv; u < 50; u += 4)
        stage16(gsrc + (size_t)u * 512 + lane * 8, sm + u * 512);
    __syncthreads();

    int mg = wv & 1, ng = wv >> 1;
    fx4 acc[2][2];
    #pragma unroll
    for (int i = 0; i < 2; ++i)
        #pragma unroll
        for (int j = 0; j < 2; ++j) acc[i][j] = (fx4){0.f, 0.f, 0.f, 0.f};
    for (int tap = 0; tap < 9; ++tap) {
        int kh = tap / 3, kw = tap % 3;
        #pragma unroll
        for (int ks = 0; ks < 4; ++ks) {
            bf16x8 bfr[2], af[2];
            #pragma unroll
            for (int nt = 0; nt < 2; ++nt)
                bfr[nt] = *(const bf16x8*)(wr + (size_t)((ng * 2 + nt) * 16 + n16) * 1152 + tap * 128 + ks * 32 + quad * 8);
            #pragma unroll
            for (int mt = 0; mt < 2; ++mt) {
                int px = kw + (mg * 2 + mt) * 16 + n16;            // 0..65
                af[mt] = *(const bf16x8*)(sm + (kh * 66 + px) * 128 + ks * 32 + quad * 8);
            }
            #pragma unroll
            for (int mt = 0; mt < 2; ++mt)
                #pragma unroll
                for (int nt = 0; nt < 2; ++nt)
                    acc[mt][nt] = MFMA16(af[mt], bfr[nt], acc[mt][nt]);
        }
    }
    #pragma unroll
    for (int nt = 0; nt < 2; ++nt) {
        int co = (ng * 2 + nt) * 16 + n16;
        float bs = bias[co];
        #pragma unroll
        for (int mt = 0; mt < 2; ++mt) {
            #pragma unroll
            for (int r = 0; r < 4; ++r) {
                int ow = (mg * 2 + mt) * 16 + quad * 4 + r;
                z[((size_t)(b * 64 + oh) * 64 + ow) * 64 + co] =
                    f2bf(fmaxf(acc[mt][nt][r] + bs, 0.f));
            }
        }
    }
}

// ------------------------- VQ ----------------------------------------------
__global__ __launch_bounds__(256) void vq_k(
    const ushort_t* __restrict__ z, const float* __restrict__ emb,
    ushort_t* __restrict__ qpad, float* __restrict__ loss_acc)
{
    __shared__ float se2[512];
    __shared__ float red[256];
    int tid = threadIdx.x;
    for (int k = tid; k < 512; k += 256) {
        const float* e = emb + k * 64;
        float s = 0.f;
        for (int d = 0; d < 64; ++d) s = fmaf(e[d], e[d], s);
        se2[k] = s;
    }
    __syncthreads();
    int p = blockIdx.x * 256 + tid;
    int wc = p & 63, h = (p >> 6) & 63, b = p >> 12;
    const unsigned* zr = (const unsigned*)(z + (size_t)p * 64);
    float zv[64];
    #pragma unroll
    for (int t = 0; t < 32; ++t) {
        unsigned u = zr[t];
        zv[2 * t]     = __uint_as_float(u << 16);
        zv[2 * t + 1] = __uint_as_float(u & 0xFFFF0000u);
    }
    float best = 1e30f;
    int bi = 0;
    for (int k = 0; k < 512; ++k) {
        const float4* e4 = (const float4*)(emb + k * 64);
        float d0 = 0.f, d1 = 0.f, d2 = 0.f, d3 = 0.f;
        #pragma unroll
        for (int t = 0; t < 16; ++t) {
            float4 e = e4[t];
            d0 = fmaf(e.x, zv[4 * t + 0], d0);
            d1 = fmaf(e.y, zv[4 * t + 1], d1);
            d2 = fmaf(e.z, zv[4 * t + 2], d2);
            d3 = fmaf(e.w, zv[4 * t + 3], d3);
        }
        float dot = (d0 + d1) + (d2 + d3);
        float score = fmaf(-2.f, dot, se2[k]);
        if (score < best) { best = score; bi = k; }
    }
    float lsum = 0.f;
    const float* e = emb + bi * 64;
    unsigned* qp = (unsigned*)(qpad + ((size_t)(b * 66 + h + 1) * 66 + (wc + 1)) * 64);
    #pragma unroll
    for (int t = 0; t < 32; ++t) {
        float e0 = e[2 * t], e1 = e[2 * t + 1];
        float f0 = e0 - zv[2 * t], f1 = e1 - zv[2 * t + 1];
        lsum = fmaf(f0, f0, lsum);
        lsum = fmaf(f1, f1, lsum);
        qp[t] = (unsigned)f2bf(e0) | ((unsigned)f2bf(e1) << 16);
    }
    red[tid] = lsum;
    __syncthreads();
    for (int s = 128; s > 0; s >>= 1) {
        if (tid < s) red[tid] += red[tid + s];
        __syncthreads();
    }
    if (tid == 0) atomicAdd(loss_acc, red[0]);
}

__global__ void loss_fin_k(const float* __restrict__ acc, float* __restrict__ out)
{
    out[0] = 1.25f * acc[0] / 8388608.0f;
}

// ------------------------- deconv1 MFMA (LDS-staged) -----------------------
// q_pad chunk -> d1c[8][130][130][128]. Block=(b,oh): stage qpad rows
// [ihp0-1, ihp0] (16896B -> 17 chunks, 512B over-read ok). M=128(2par x 64),
// N=128, K=256/par. Wave: parity=wv&1, 2mt x 8nt.
__global__ __launch_bounds__(256) void deconv1_mfma(
    const ushort_t* __restrict__ q, const ushort_t* __restrict__ wr,
    const float* __restrict__ bias, ushort_t* __restrict__ d1)
{
    __shared__ ushort_t sm[8704];           // 2 x 66 x 64 (+tail)
    int tid = threadIdx.x;
    int wv = tid >> 6, lane = tid & 63;
    int n16 = lane & 15, quad = lane >> 4;
    int blk = blockIdx.x;                   // 1024
    int oh = blk & 127, b = blk >> 7;
    int h0 = (oh + 1) & 1;
    int ihp0 = ((oh + 1 - h0) >> 1) + 1;    // 1..65
    const ushort_t* gsrc = q + (size_t)(b * 66 + ihp0 - 1) * 66 * 64;
    for (int u = wv; u < 17; u += 4)
        stage16(gsrc + (size_t)u * 512 + lane * 8, sm + u * 512);
    __syncthreads();

    int pw = wv & 1, mg = wv >> 1;          // parity, mts {mg*2,mg*2+1}
    int q0 = 1 - pw;
    fx4 acc[2][8];
    #pragma unroll
    for (int i = 0; i < 2; ++i)
        #pragma unroll
        for (int j = 0; j < 8; ++j) acc[i][j] = (fx4){0.f, 0.f, 0.f, 0.f};
    #pragma unroll
    for (int t2 = 0; t2 < 2; ++t2) {
        int kh = h0 + 2 * t2;
        int lrow = 1 - t2;                  // kh=h0 -> ihp0 (row1); kh=h0+2 -> row0
        #pragma unroll
        for (int t3 = 0; t3 < 2; ++t3) {
            int kw = q0 + 2 * t3;
            int cadd = pw + (t3 == 0 ? 1 : 0);
            int tap = kh * 4 + kw;
            #pragma unroll
            for (int ks = 0; ks < 2; ++ks) {
                bf16x8 bfr[8], af[2];
                #pragma unroll
                for (int nt = 0; nt < 8; ++nt)
                    bfr[nt] = *(const bf16x8*)(wr + (size_t)(nt * 16 + n16) * 1024 + tap * 64 + ks * 32 + quad * 8);
                #pragma unroll
                for (int mt = 0; mt < 2; ++mt) {
                    int px = cadd + (mg * 2 + mt) * 16 + n16;      // 0..65
                    af[mt] = *(const bf16x8*)(sm + (lrow * 66 + px) * 64 + ks * 32 + quad * 8);
                }
                #pragma unroll
                for (int mt = 0; mt < 2; ++mt)
                    #pragma unroll
                    for (int nt = 0; nt < 8; ++nt)
                        acc[mt][nt] = MFMA16(af[mt], bfr[nt], acc[mt][nt]);
            }
        }
    }
    #pragma unroll
    for (int nt = 0; nt < 8; ++nt) {
        int co = nt * 16 + n16;
        float bs = bias[co];
        #pragma unroll
        for (int mt = 0; mt < 2; ++mt) {
            #pragma unroll
            for (int r = 0; r < 4; ++r) {
                int ow = 2 * ((mg * 2 + mt) * 16 + quad * 4 + r) + pw;
                d1[((size_t)(b * 130 + oh + 1) * 130 + (ow + 1)) * 128 + co] =
                    f2bf(fmaxf(acc[mt][nt][r] + bs, 0.f));
            }
        }
    }
}

// ------------------------- deconv2 MFMA (LDS-staged) -----------------------
// d1c -> d2c[8][258][258][64]. Block=(b,oh): stage d1c rows [ihp0-1, ihp0]
// (66560B = 65 chunks exact). M=256(2par x 128), N=64, K=512/par.
// Wave: parity=wv&1, 4mt x 4nt.
__global__ __launch_bounds__(256) void deconv2_mfma(
    const ushort_t* __restrict__ d1, const ushort_t* __restrict__ wr,
    const float* __restrict__ bias, ushort_t* __restrict__ d2)
{
    __shared__ ushort_t sm[33280];          // 2 x 130 x 128
    int tid = threadIdx.x;
    int wv = tid >> 6, lane = tid & 63;
    int n16 = lane & 15, quad = lane >> 4;
    int blk = blockIdx.x;                   // 2048
    int oh = blk & 255, b = blk >> 8;
    int h0 = (oh + 1) & 1;
    int ihp0 = ((oh + 1 - h0) >> 1) + 1;    // 1..129
    const ushort_t* gsrc = d1 + (size_t)(b * 130 + ihp0 - 1) * 130 * 128;
    for (int u = wv; u < 65; u += 4)
        stage16(gsrc + (size_t)u * 512 + lane * 8, sm + u * 512);
    __syncthreads();

    int pw = wv & 1, mg = wv >> 1;          // parity, mts {mg*4..mg*4+3}
    int q0 = 1 - pw;
    fx4 acc[4][4];
    #pragma unroll
    for (int i = 0; i < 4; ++i)
        #pragma unroll
        for (int j = 0; j < 4; ++j) acc[i][j] = (fx4){0.f, 0.f, 0.f, 0.f};
    #pragma unroll
    for (int t2 = 0; t2 < 2; ++t2) {
        int kh = h0 + 2 * t2;
        int lrow = 1 - t2;
        #pragma unroll
        for (int t3 = 0; t3 < 2; ++t3) {
            int kw = q0 + 2 * t3;
            int cadd = pw + (t3 == 0 ? 1 : 0);
            int tap = kh * 4 + kw;
            #pragma unroll
            for (int ks = 0; ks < 4; ++ks) {
                bf16x8 bfr[4], af[4];
                #pragma unroll
                for (int nt = 0; nt < 4; ++nt)
                    bfr[nt] = *(const bf16x8*)(wr + (size_t)(nt * 16 + n16) * 2048 + tap * 128 + ks * 32 + quad * 8);
                #pragma unroll
                for (int mt = 0; mt < 4; ++mt) {
                    int px = cadd + (mg * 4 + mt) * 16 + n16;      // 0..129
                    af[mt] = *(const bf16x8*)(sm + (lrow * 130 + px) * 128 + ks * 32 + quad * 8);
                }
                #pragma unroll
                for (int mt = 0; mt < 4; ++mt)
                    #pragma unroll
                    for (int nt = 0; nt < 4; ++nt)
                        acc[mt][nt] = MFMA16(af[mt], bfr[nt], acc[mt][nt]);
            }
        }
    }
    #pragma unroll
    for (int nt = 0; nt < 4; ++nt) {
        int co = nt * 16 + n16;
        float bs = bias[co];
        #pragma unroll
        for (int mt = 0; mt < 4; ++mt) {
            #pragma unroll
            for (int r = 0; r < 4; ++r) {
                int ow = 2 * ((mg * 4 + mt) * 16 + quad * 4 + r) + pw;
                d2[((size_t)(b * 258 + oh + 1) * 258 + (ow + 1)) * 64 + co] =
                    f2bf(fmaxf(acc[mt][nt][r] + bs, 0.f));
            }
        }
    }
}

// ------------------------- deconv3 MFMA (LDS-staged) -----------------------
// d2c -> out chunk (8,3,256,256) f32 sigmoid. Block=(b,oh,half): stage 3 row
// windows of 136px (17 chunks each, over-read <=768B within workspace).
// M=128, N=16(3 used), K=576. Wave: 2mt.
__global__ __launch_bounds__(256) void deconv3_mfma(
    const ushort_t* __restrict__ d2, const ushort_t* __restrict__ wr,
    const float* __restrict__ bias, float* __restrict__ out)
{
    __shared__ ushort_t sm[26112];          // 3 x 136 x 64
    int tid = threadIdx.x;
    int wv = tid >> 6, lane = tid & 63;
    int n16 = lane & 15, quad = lane >> 4;
    int blk = blockIdx.x;                   // 4096
    int half = blk & 1;
    int oh = (blk >> 1) & 255;
    int b = blk >> 9;
    for (int u = wv; u < 51; u += 4) {
        int c = u / 17, uu = u - c * 17;
        const ushort_t* gsrc = d2 + ((size_t)(b * 258 + oh + c) * 258 + half * 128) * 64;
        stage16(gsrc + (size_t)uu * 512 + lane * 8, sm + c * 8704 + uu * 512);
    }
    __syncthreads();

    fx4 acc[2];
    #pragma unroll
    for (int i = 0; i < 2; ++i) acc[i] = (fx4){0.f, 0.f, 0.f, 0.f};
    for (int tap = 0; tap < 9; ++tap) {
        int kh = tap / 3, kw = tap % 3;
        int c = 2 - kh;
        #pragma unroll
        for (int ks = 0; ks < 2; ++ks) {
            bf16x8 bfr = *(const bf16x8*)(wr + (size_t)n16 * 576 + tap * 64 + ks * 32 + quad * 8);
            bf16x8 af[2];
            #pragma unroll
            for (int mt = 0; mt < 2; ++mt) {
                int px = (2 - kw) + (wv * 2 + mt) * 16 + n16;      // 0..129
                af[mt] = *(const bf16x8*)(sm + (c * 136 + px) * 64 + ks * 32 + quad * 8);
            }
            #pragma unroll
            for (int mt = 0; mt < 2; ++mt)
                acc[mt] = MFMA16(af[mt], bfr, acc[mt]);
        }
    }
    int co = n16;
    if (co < 3) {
        float bs = bias[co];
        #pragma unroll
        for (int mt = 0; mt < 2; ++mt) {
            int ow0 = half * 128 + (wv * 2 + mt) * 16 + quad * 4;
            float4 v;
            v.x = 1.f / (1.f + __expf(-(acc[mt][0] + bs)));
            v.y = 1.f / (1.f + __expf(-(acc[mt][1] + bs)));
            v.z = 1.f / (1.f + __expf(-(acc[mt][2] + bs)));
            v.w = 1.f / (1.f + __expf(-(acc[mt][3] + bs)));
            *(float4*)(out + (((size_t)b * 3 + co) * 256 + oh) * 256 + ow0) = v;
        }
    }
}

// ---------------------------------------------------------------------------
extern "C" void kernel_launch(void* const* d_in, const int* in_sizes, int n_in,
                              void* d_out, int out_size, void* d_ws, size_t ws_size,
                              hipStream_t stream)
{
    const float* x   = (const float*)d_in[0];
    const float* w1  = (const float*)d_in[1];
    const float* b1  = (const float*)d_in[2];
    const float* w2  = (const float*)d_in[3];
    const float* b2  = (const float*)d_in[4];
    const float* w3  = (const float*)d_in[5];
    const float* b3  = (const float*)d_in[6];
    const float* emb = (const float*)d_in[7];
    const float* dw1 = (const float*)d_in[8];
    const float* db1 = (const float*)d_in[9];
    const float* dw2 = (const float*)d_in[10];
    const float* db2 = (const float*)d_in[11];
    const float* dw3 = (const float*)d_in[12];
    const float* db3 = (const float*)d_in[13];
    float* xout = (float*)d_out;

    ushort_t* xp   = (ushort_t*)d_ws;            // 32*130*130*64 = 34,611,200
    ushort_t* h2p  = xp   + 34611200;            // 32*66*66*128  = 17,842,176
    ushort_t* qpad = h2p  + 17842176;            // 32*66*66*64   =  8,921,088
    ushort_t* d1c  = qpad + 8921088;             //  8*130*130*128= 17,305,600
    ushort_t* d2c  = d1c  + 17305600;            //  8*258*258*64 = 34,080,768
    ushort_t* zb   = d2c  + 34080768;            // 32*64*64*64   =  8,388,608
    ushort_t* wr2  = zb   + 8388608;             // 131,072
    ushort_t* wr3  = wr2  + 131072;              //  73,728
    ushort_t* wd1  = wr3  + 73728;               // 131,072
    ushort_t* wd2  = wd1  + 131072;              // 131,072
    ushort_t* wd3  = wd2  + 131072;              //   9,216
    float*    lac  = (float*)(wd3 + 9216);

    // zero only halos (interiors are fully overwritten each call)
    halo_zero<<<516, 256, 0, stream>>>(xp,   32, 130, 130, 8);
    halo_zero<<<520, 256, 0, stream>>>(h2p,  32,  66,  66, 16);
    halo_zero<<<260, 256, 0, stream>>>(qpad, 32,  66,  66, 8);
    halo_zero<<<258, 256, 0, stream>>>(d1c,   8, 130, 130, 16);
    halo_zero<<<257, 256, 0, stream>>>(d2c,   8, 258, 258, 8);
    zero_k<<<1, 1, 0, stream>>>(lac);

    repack_w2<<<512, 256, 0, stream>>>(w2, wr2);
    repack_w3<<<288, 256, 0, stream>>>(w3, wr3);
    repack_d1<<<512, 256, 0, stream>>>(dw1, wd1);
    repack_d2<<<512, 256, 0, stream>>>(dw2, wd2);
    repack_d3<<<36,  256, 0, stream>>>(dw3, wd3);

    conv1_k   <<<32768, 256, 0, stream>>>(x, w1, b1, xp);
    conv2_mfma<<<2048,  256, 0, stream>>>(xp, wr2, b2, h2p);
    conv3_mfma<<<2048,  256, 0, stream>>>(h2p, wr3, b3, zb);
    vq_k      <<<512,   256, 0, stream>>>(zb, emb, qpad, lac);
    loss_fin_k<<<1, 1, 0, stream>>>(lac, xout + 6291456);

    for (int c0 = 0; c0 < 32; c0 += 8) {
        deconv1_mfma<<<1024, 256, 0, stream>>>(qpad + (size_t)c0 * 278784, wd1, db1, d1c);
        deconv2_mfma<<<2048, 256, 0, stream>>>(d1c, wd2, db2, d2c);
        deconv3_mfma<<<4096, 256, 0, stream>>>(d2c, wd3, db3, xout + (size_t)c0 * 196608);
    }
}

// Round 6
// 892.513 us; speedup vs baseline: 16.9882x; 1.6804x over previous
//
#include <hip/hip_runtime.h>
#include <math.h>

// ---------------------------------------------------------------------------
// VQ-VAE forward, round 5.
// vs round 4: (1) conv1 -> MFMA via padded [258][258][4ci] bf16 input,
// (2) all weights in lane-swizzled layout -> B-frag loads are coalesced 1KB
// wave reads instead of 16-line gathers, (3) XOR swizzle (16B slots,
// s ^ ((s>>3)&7)) on all LDS staging to break the 128B-stride bank conflicts
// on A-reads (16-way -> <=4-way).
// MFMA 16x16x32 layouts (m89): A/B frag row=lane&15, k=(lane>>4)*8+j.
// C/D: col(n)=lane&15, row(m)=(lane>>4)*4+reg.
// ---------------------------------------------------------------------------

typedef __attribute__((ext_vector_type(8))) short bf16x8;
typedef __attribute__((ext_vector_type(4))) float fx4;
typedef unsigned short ushort_t;
#define MFMA16(a, b, c) __builtin_amdgcn_mfma_f32_16x16x32_bf16(a, b, c, 0, 0, 0)

__device__ inline ushort_t f2bf(float f) {
    unsigned u = __float_as_uint(f);
    u += 0x7FFFu + ((u >> 16) & 1u);
    return (ushort_t)(u >> 16);
}

// async global->LDS 16B per lane: g per-lane, l wave-uniform (lane i -> l+i*16)
__device__ __forceinline__ void stage16(const ushort_t* g, ushort_t* l) {
#if __has_builtin(__builtin_amdgcn_global_load_lds)
    __builtin_amdgcn_global_load_lds(
        (const __attribute__((address_space(1))) unsigned int*)g,
        (__attribute__((address_space(3))) unsigned int*)l, 16, 0, 0);
#else
    int lane = threadIdx.x & 63;
    *(int4*)(l + lane * 8) = *(const int4*)g;
#endif
}

// XOR swizzle over 16B slots (self-inverse). Staged chunks are 64-slot aligned.
__device__ __forceinline__ int swz(int s) { return s ^ ((s >> 3) & 7); }
__device__ __forceinline__ bf16x8 sld(const ushort_t* sm, int gslot) {
    return *(const bf16x8*)(sm + (size_t)swz(gslot) * 8);
}

__global__ void zero_k(float* __restrict__ p) { p[0] = 0.f; }

// zero halo of [B][H][W][C8*8] bf16 buffer
__global__ __launch_bounds__(256) void halo_zero(
    ushort_t* __restrict__ buf, int B, int H, int W, int C8)
{
    int idx = blockIdx.x * 256 + threadIdx.x;
    int perim = 2 * W + 2 * (H - 2);
    if (idx >= B * perim * C8) return;
    int c8 = idx % C8;
    int t = idx / C8;
    int p = t % perim;
    int b = t / perim;
    int r, col;
    if (p < W) { r = 0; col = p; }
    else if (p < 2 * W) { r = H - 1; col = p - W; }
    else { int pp = p - 2 * W; r = 1 + (pp >> 1); col = (pp & 1) ? (W - 1) : 0; }
    size_t off = ((((size_t)b * H + r) * W + col) * C8 + c8) * 8;
    *(int4*)(buf + off) = (int4){0, 0, 0, 0};
}

// zero halo of x4 [32][258][258][4]
__global__ __launch_bounds__(256) void x4_halo(ushort_t* __restrict__ x4)
{
    int idx = blockIdx.x * 256 + threadIdx.x;
    if (idx >= 32 * 1032) return;
    int b = idx / 1032;
    int s = idx % 1032;
    int side = s / 258, c = s % 258;
    int r, col;
    if (side == 0) { r = 0; col = c; }
    else if (side == 1) { r = 257; col = c; }
    else if (side == 2) { r = c; col = 0; }
    else { r = c; col = 257; }
    *(uint2*)(x4 + ((size_t)(b * 258 + r) * 258 + col) * 4) = (uint2){0, 0};
}

// x (32,3,256,256) f32 -> x4 [32][258][258][4] bf16 (ci=3 zero)
__global__ __launch_bounds__(256) void cast_x4(
    const float* __restrict__ x, ushort_t* __restrict__ x4)
{
    int i = blockIdx.x * 256 + threadIdx.x;   // 2,097,152
    int w = i & 255, h = (i >> 8) & 255, b = i >> 16;
    size_t base = ((size_t)b * 3 * 256 + h) * 256 + w;
    float v0 = x[base];
    float v1 = x[base + 65536];
    float v2 = x[base + 131072];
    uint2 o;
    o.x = (unsigned)f2bf(v0) | ((unsigned)f2bf(v1) << 16);
    o.y = (unsigned)f2bf(v2);
    *(uint2*)(x4 + ((size_t)(b * 258 + h + 1) * 258 + (w + 1)) * 4) = o;
}

// ---------------- weight repacks: swizzled layout ---------------------------
// off = ((t*numC + c)*64 + lane)*8 + j ; co = t*16 + (lane&15);
// k = c*32 + (lane>>4)*8 + j
// w1 [64co][3ci][4][4] -> 4096 ; k: kh=k>>4, kw=(k>>2)&3, ci=k&3
__global__ __launch_bounds__(256) void repack_w1(const float* __restrict__ w, ushort_t* __restrict__ o) {
    int i = blockIdx.x * 256 + threadIdx.x;   // 4096
    int j = i & 7, lane = (i >> 3) & 63, tc = i >> 9;
    int c = tc & 1, t = tc >> 1;
    int co = t * 16 + (lane & 15);
    int k = c * 32 + (lane >> 4) * 8 + j;
    int kh = k >> 4, kw = (k >> 2) & 3, ci = k & 3;
    o[i] = (ci < 3) ? f2bf(w[((co * 3 + ci) * 4 + kh) * 4 + kw]) : (ushort_t)0;
}
// w2 [128co][64ci][4][4] -> 131072 ; numC=32 ; k: tap=k>>6, ci=k&63
__global__ __launch_bounds__(256) void repack_w2(const float* __restrict__ w, ushort_t* __restrict__ o) {
    int i = blockIdx.x * 256 + threadIdx.x;   // 131072
    int j = i & 7, lane = (i >> 3) & 63, tc = i >> 9;
    int c = tc & 31, t = tc >> 5;
    int co = t * 16 + (lane & 15);
    int k = c * 32 + (lane >> 4) * 8 + j;
    int tap = k >> 6, ci = k & 63, kh = tap >> 2, kw = tap & 3;
    o[i] = f2bf(w[((co * 64 + ci) * 4 + kh) * 4 + kw]);
}
// w3 [64co][128ci][3][3] -> 73728 ; numC=36 ; tap=k>>7, ci=k&127
__global__ __launch_bounds__(256) void repack_w3(const float* __restrict__ w, ushort_t* __restrict__ o) {
    int i = blockIdx.x * 256 + threadIdx.x;   // 73728
    int j = i & 7, lane = (i >> 3) & 63, tc = i >> 9;
    int c = tc % 36, t = tc / 36;
    int co = t * 16 + (lane & 15);
    int k = c * 32 + (lane >> 4) * 8 + j;
    int tap = k >> 7, ci = k & 127, kh = tap / 3, kw = tap % 3;
    o[i] = f2bf(w[((co * 128 + ci) * 3 + kh) * 3 + kw]);
}
// dw1 [64ci][128co][4][4] -> 131072 ; numC=32
__global__ __launch_bounds__(256) void repack_d1(const float* __restrict__ w, ushort_t* __restrict__ o) {
    int i = blockIdx.x * 256 + threadIdx.x;   // 131072
    int j = i & 7, lane = (i >> 3) & 63, tc = i >> 9;
    int c = tc & 31, t = tc >> 5;
    int co = t * 16 + (lane & 15);
    int k = c * 32 + (lane >> 4) * 8 + j;
    int tap = k >> 6, ci = k & 63, kh = tap >> 2, kw = tap & 3;
    o[i] = f2bf(w[((ci * 128 + co) * 4 + kh) * 4 + kw]);
}
// dw2 [128ci][64co][4][4] -> 131072 ; numC=64 ; tap=k>>7, ci=k&127
__global__ __launch_bounds__(256) void repack_d2(const float* __restrict__ w, ushort_t* __restrict__ o) {
    int i = blockIdx.x * 256 + threadIdx.x;   // 131072
    int j = i & 7, lane = (i >> 3) & 63, tc = i >> 9;
    int c = tc & 63, t = tc >> 6;
    int co = t * 16 + (lane & 15);
    int k = c * 32 + (lane >> 4) * 8 + j;
    int tap = k >> 7, ci = k & 127, kh = tap >> 2, kw = tap & 3;
    o[i] = f2bf(w[((ci * 64 + co) * 4 + kh) * 4 + kw]);
}
// dw3 [64ci][3co][3][3] -> 9216 ; numC=18, t=0 ; tap=k>>6, ci=k&63
__global__ __launch_bounds__(256) void repack_d3(const float* __restrict__ w, ushort_t* __restrict__ o) {
    int i = blockIdx.x * 256 + threadIdx.x;   // 9216
    if (i >= 9216) return;
    int j = i & 7, lane = (i >> 3) & 63, c = i >> 9;
    int co = lane & 15;
    int k = c * 32 + (lane >> 4) * 8 + j;
    int tap = k >> 6, ci = k & 63, kh = tap / 3, kw = tap % 3;
    o[i] = (co < 3) ? f2bf(w[((ci * 3 + co) * 3 + kh) * 3 + kw]) : (ushort_t)0;
}

// ------------------------- conv1 MFMA ---------------------------------------
// x4[32][258][258][4] -> xp[32][130][130][64]. K=64 (kh*16+kw*4+ci).
// Block=(b,oh): stage 4 rows (8256B, 9 chunks). M=128 x N=64. Wave: 2mt x 4nt.
__global__ __launch_bounds__(256) void conv1_mfma(
    const ushort_t* __restrict__ x4, const ushort_t* __restrict__ wr,
    const float* __restrict__ bias, ushort_t* __restrict__ xp)
{
    __shared__ ushort_t sm[4608];
    int tid = threadIdx.x;
    int wv = tid >> 6, lane = tid & 63;
    int n16 = lane & 15, quad = lane >> 4;
    int blk = blockIdx.x;                   // 4096
    int oh = blk & 127, b = blk >> 7;
    const ushort_t* gsrc = x4 + (size_t)(b * 258 + 2 * oh) * 1032;
    int sl = lane ^ ((lane >> 3) & 7);
    for (int u = wv; u < 9; u += 4)
        stage16(gsrc + u * 512 + sl * 8, sm + u * 512);
    __syncthreads();

    fx4 acc[2][4];
    #pragma unroll
    for (int i = 0; i < 2; ++i)
        #pragma unroll
        for (int j = 0; j < 4; ++j) acc[i][j] = (fx4){0.f, 0.f, 0.f, 0.f};
    #pragma unroll
    for (int c = 0; c < 2; ++c) {
        int kh = 2 * c + (quad >> 1);
        int kwh = quad & 1;
        bf16x8 af[2], bfr[4];
        #pragma unroll
        for (int mt = 0; mt < 2; ++mt) {
            int ow = (wv * 2 + mt) * 16 + n16;
            af[mt] = sld(sm, kh * 129 + ow + kwh);
        }
        #pragma unroll
        for (int nt = 0; nt < 4; ++nt)
            bfr[nt] = *(const bf16x8*)(wr + ((size_t)(nt * 2 + c) * 64 + lane) * 8);
        #pragma unroll
        for (int mt = 0; mt < 2; ++mt)
            #pragma unroll
            for (int nt = 0; nt < 4; ++nt)
                acc[mt][nt] = MFMA16(af[mt], bfr[nt], acc[mt][nt]);
    }
    #pragma unroll
    for (int nt = 0; nt < 4; ++nt) {
        int co = nt * 16 + n16;
        float bs = bias[co];
        #pragma unroll
        for (int mt = 0; mt < 2; ++mt) {
            #pragma unroll
            for (int r = 0; r < 4; ++r) {
                int ow = (wv * 2 + mt) * 16 + quad * 4 + r;
                xp[((size_t)(b * 130 + oh + 1) * 130 + (ow + 1)) * 64 + co] =
                    f2bf(fmaxf(acc[mt][nt][r] + bs, 0.f));
            }
        }
    }
}

// ------------------------- conv2 MFMA ---------------------------------------
// xp[32][130][130][64] -> h2p[32][66][66][128]. Block=(b,oh): stage 4 rows
// (66560B, 65 chunks). M=64 x N=128, K=1024. Wave: 2mt x 4nt.
__global__ __launch_bounds__(256) void conv2_mfma(
    const ushort_t* __restrict__ xp, const ushort_t* __restrict__ wr,
    const float* __restrict__ bias, ushort_t* __restrict__ h2p)
{
    __shared__ ushort_t sm[33280];
    int tid = threadIdx.x;
    int wv = tid >> 6, lane = tid & 63;
    int n16 = lane & 15, quad = lane >> 4;
    int blk = blockIdx.x;                   // 2048
    int oh = blk & 63, b = blk >> 6;
    const ushort_t* gsrc = xp + (size_t)(b * 130 + 2 * oh) * 130 * 64;
    int sl = lane ^ ((lane >> 3) & 7);
    for (int u = wv; u < 65; u += 4)
        stage16(gsrc + (size_t)u * 512 + sl * 8, sm + u * 512);
    __syncthreads();

    int mg = wv & 1, ng = wv >> 1;
    fx4 acc[2][4];
    #pragma unroll
    for (int i = 0; i < 2; ++i)
        #pragma unroll
        for (int j = 0; j < 4; ++j) acc[i][j] = (fx4){0.f, 0.f, 0.f, 0.f};
    for (int tap = 0; tap < 16; ++tap) {
        int kh = tap >> 2, kw = tap & 3;
        #pragma unroll
        for (int ks = 0; ks < 2; ++ks) {
            bf16x8 bfr[4], af[2];
            #pragma unroll
            for (int nt = 0; nt < 4; ++nt)
                bfr[nt] = *(const bf16x8*)(wr + ((size_t)((ng * 4 + nt) * 32 + tap * 2 + ks) * 64 + lane) * 8);
            #pragma unroll
            for (int mt = 0; mt < 2; ++mt) {
                int px = kw + 2 * ((mg * 2 + mt) * 16 + n16);      // 0..129
                af[mt] = sld(sm, (kh * 130 + px) * 8 + ks * 4 + quad);
            }
            #pragma unroll
            for (int mt = 0; mt < 2; ++mt)
                #pragma unroll
                for (int nt = 0; nt < 4; ++nt)
                    acc[mt][nt] = MFMA16(af[mt], bfr[nt], acc[mt][nt]);
        }
    }
    #pragma unroll
    for (int nt = 0; nt < 4; ++nt) {
        int co = (ng * 4 + nt) * 16 + n16;
        float bs = bias[co];
        #pragma unroll
        for (int mt = 0; mt < 2; ++mt) {
            #pragma unroll
            for (int r = 0; r < 4; ++r) {
                int ow = (mg * 2 + mt) * 16 + quad * 4 + r;
                h2p[((size_t)(b * 66 + oh + 1) * 66 + (ow + 1)) * 128 + co] =
                    f2bf(fmaxf(acc[mt][nt][r] + bs, 0.f));
            }
        }
    }
}

// ------------------------- conv3 MFMA ---------------------------------------
// h2p -> z[32][64][64][64]. Block=(b,oh): stage 3 rows (50 chunks).
// M=64 x N=64, K=1152. Wave: 2mt x 2nt.
__global__ __launch_bounds__(256) void conv3_mfma(
    const ushort_t* __restrict__ hp, const ushort_t* __restrict__ wr,
    const float* __restrict__ bias, ushort_t* __restrict__ z)
{
    __shared__ ushort_t sm[25600];
    int tid = threadIdx.x;
    int wv = tid >> 6, lane = tid & 63;
    int n16 = lane & 15, quad = lane >> 4;
    int blk = blockIdx.x;                   // 2048
    int oh = blk & 63, b = blk >> 6;
    const ushort_t* gsrc = hp + (size_t)(b * 66 + oh) * 66 * 128;
    int sl = lane ^ ((lane >> 3) & 7);
    for (int u = wv; u < 50; u += 4)
        stage16(gsrc + (size_t)u * 512 + sl * 8, sm + u * 512);
    __syncthreads();

    int mg = wv & 1, ng = wv >> 1;
    fx4 acc[2][2];
    #pragma unroll
    for (int i = 0; i < 2; ++i)
        #pragma unroll
        for (int j = 0; j < 2; ++j) acc[i][j] = (fx4){0.f, 0.f, 0.f, 0.f};
    for (int tap = 0; tap < 9; ++tap) {
        int kh = tap / 3, kw = tap % 3;
        #pragma unroll
        for (int ks = 0; ks < 4; ++ks) {
            bf16x8 bfr[2], af[2];
            #pragma unroll
            for (int nt = 0; nt < 2; ++nt)
                bfr[nt] = *(const bf16x8*)(wr + ((size_t)((ng * 2 + nt) * 36 + tap * 4 + ks) * 64 + lane) * 8);
            #pragma unroll
            for (int mt = 0; mt < 2; ++mt) {
                int px = kw + (mg * 2 + mt) * 16 + n16;            // 0..65
                af[mt] = sld(sm, (kh * 66 + px) * 16 + ks * 4 + quad);
            }
            #pragma unroll
            for (int mt = 0; mt < 2; ++mt)
                #pragma unroll
                for (int nt = 0; nt < 2; ++nt)
                    acc[mt][nt] = MFMA16(af[mt], bfr[nt], acc[mt][nt]);
        }
    }
    #pragma unroll
    for (int nt = 0; nt < 2; ++nt) {
        int co = (ng * 2 + nt) * 16 + n16;
        float bs = bias[co];
        #pragma unroll
        for (int mt = 0; mt < 2; ++mt) {
            #pragma unroll
            for (int r = 0; r < 4; ++r) {
                int ow = (mg * 2 + mt) * 16 + quad * 4 + r;
                z[((size_t)(b * 64 + oh) * 64 + ow) * 64 + co] =
                    f2bf(fmaxf(acc[mt][nt][r] + bs, 0.f));
            }
        }
    }
}

// ------------------------- VQ -----------------------------------------------
__global__ __launch_bounds__(256) void vq_k(
    const ushort_t* __restrict__ z, const float* __restrict__ emb,
    ushort_t* __restrict__ qpad, float* __restrict__ loss_acc)
{
    __shared__ float se2[512];
    __shared__ float red[256];
    int tid = threadIdx.x;
    for (int k = tid; k < 512; k += 256) {
        const float* e = emb + k * 64;
        float s = 0.f;
        for (int d = 0; d < 64; ++d) s = fmaf(e[d], e[d], s);
        se2[k] = s;
    }
    __syncthreads();
    int p = blockIdx.x * 256 + tid;
    int wc = p & 63, h = (p >> 6) & 63, b = p >> 12;
    const unsigned* zr = (const unsigned*)(z + (size_t)p * 64);
    float zv[64];
    #pragma unroll
    for (int t = 0; t < 32; ++t) {
        unsigned u = zr[t];
        zv[2 * t]     = __uint_as_float(u << 16);
        zv[2 * t + 1] = __uint_as_float(u & 0xFFFF0000u);
    }
    float best = 1e30f;
    int bi = 0;
    for (int k = 0; k < 512; ++k) {
        const float4* e4 = (const float4*)(emb + k * 64);
        float d0 = 0.f, d1 = 0.f, d2 = 0.f, d3 = 0.f;
        #pragma unroll
        for (int t = 0; t < 16; ++t) {
            float4 e = e4[t];
            d0 = fmaf(e.x, zv[4 * t + 0], d0);
            d1 = fmaf(e.y, zv[4 * t + 1], d1);
            d2 = fmaf(e.z, zv[4 * t + 2], d2);
            d3 = fmaf(e.w, zv[4 * t + 3], d3);
        }
        float dot = (d0 + d1) + (d2 + d3);
        float score = fmaf(-2.f, dot, se2[k]);
        if (score < best) { best = score; bi = k; }
    }
    float lsum = 0.f;
    const float* e = emb + bi * 64;
    unsigned* qp = (unsigned*)(qpad + ((size_t)(b * 66 + h + 1) * 66 + (wc + 1)) * 64);
    #pragma unroll
    for (int t = 0; t < 32; ++t) {
        float e0 = e[2 * t], e1 = e[2 * t + 1];
        float f0 = e0 - zv[2 * t], f1 = e1 - zv[2 * t + 1];
        lsum = fmaf(f0, f0, lsum);
        lsum = fmaf(f1, f1, lsum);
        qp[t] = (unsigned)f2bf(e0) | ((unsigned)f2bf(e1) << 16);
    }
    red[tid] = lsum;
    __syncthreads();
    for (int s = 128; s > 0; s >>= 1) {
        if (tid < s) red[tid] += red[tid + s];
        __syncthreads();
    }
    if (tid == 0) atomicAdd(loss_acc, red[0]);
}

__global__ void loss_fin_k(const float* __restrict__ acc, float* __restrict__ out)
{
    out[0] = 1.25f * acc[0] / 8388608.0f;
}

// ------------------------- deconv1 MFMA -------------------------------------
// q_pad chunk -> d1c[8][130][130][128]. Block=(b,oh): stage 2 rows (17 chunks).
// Wave: parity=wv&1, 2mt x 8nt.
__global__ __launch_bounds__(256) void deconv1_mfma(
    const ushort_t* __restrict__ q, const ushort_t* __restrict__ wr,
    const float* __restrict__ bias, ushort_t* __restrict__ d1)
{
    __shared__ ushort_t sm[8704];
    int tid = threadIdx.x;
    int wv = tid >> 6, lane = tid & 63;
    int n16 = lane & 15, quad = lane >> 4;
    int blk = blockIdx.x;                   // 1024
    int oh = blk & 127, b = blk >> 7;
    int h0 = (oh + 1) & 1;
    int ihp0 = ((oh + 1 - h0) >> 1) + 1;
    const ushort_t* gsrc = q + (size_t)(b * 66 + ihp0 - 1) * 66 * 64;
    int sl = lane ^ ((lane >> 3) & 7);
    for (int u = wv; u < 17; u += 4)
        stage16(gsrc + (size_t)u * 512 + sl * 8, sm + u * 512);
    __syncthreads();

    int pw = wv & 1, mg = wv >> 1;
    int q0 = 1 - pw;
    fx4 acc[2][8];
    #pragma unroll
    for (int i = 0; i < 2; ++i)
        #pragma unroll
        for (int j = 0; j < 8; ++j) acc[i][j] = (fx4){0.f, 0.f, 0.f, 0.f};
    #pragma unroll
    for (int t2 = 0; t2 < 2; ++t2) {
        int kh = h0 + 2 * t2;
        int lrow = 1 - t2;
        #pragma unroll
        for (int t3 = 0; t3 < 2; ++t3) {
            int kw = q0 + 2 * t3;
            int cadd = pw + (t3 == 0 ? 1 : 0);
            int tap = kh * 4 + kw;
            #pragma unroll
            for (int ks = 0; ks < 2; ++ks) {
                bf16x8 bfr[8], af[2];
                #pragma unroll
                for (int nt = 0; nt < 8; ++nt)
                    bfr[nt] = *(const bf16x8*)(wr + ((size_t)(nt * 32 + tap * 2 + ks) * 64 + lane) * 8);
                #pragma unroll
                for (int mt = 0; mt < 2; ++mt) {
                    int px = cadd + (mg * 2 + mt) * 16 + n16;      // 0..65
                    af[mt] = sld(sm, (lrow * 66 + px) * 8 + ks * 4 + quad);
                }
                #pragma unroll
                for (int mt = 0; mt < 2; ++mt)
                    #pragma unroll
                    for (int nt = 0; nt < 8; ++nt)
                        acc[mt][nt] = MFMA16(af[mt], bfr[nt], acc[mt][nt]);
            }
        }
    }
    #pragma unroll
    for (int nt = 0; nt < 8; ++nt) {
        int co = nt * 16 + n16;
        float bs = bias[co];
        #pragma unroll
        for (int mt = 0; mt < 2; ++mt) {
            #pragma unroll
            for (int r = 0; r < 4; ++r) {
                int ow = 2 * ((mg * 2 + mt) * 16 + quad * 4 + r) + pw;
                d1[((size_t)(b * 130 + oh + 1) * 130 + (ow + 1)) * 128 + co] =
                    f2bf(fmaxf(acc[mt][nt][r] + bs, 0.f));
            }
        }
    }
}

// ------------------------- deconv2 MFMA -------------------------------------
// d1c -> d2c[8][258][258][64]. Block=(b,oh): stage 2 rows (65 chunks).
// Wave: parity=wv&1, 4mt x 4nt.
__global__ __launch_bounds__(256) void deconv2_mfma(
    const ushort_t* __restrict__ d1, const ushort_t* __restrict__ wr,
    const float* __restrict__ bias, ushort_t* __restrict__ d2)
{
    __shared__ ushort_t sm[33280];
    int tid = threadIdx.x;
    int wv = tid >> 6, lane = tid & 63;
    int n16 = lane & 15, quad = lane >> 4;
    int blk = blockIdx.x;                   // 2048
    int oh = blk & 255, b = blk >> 8;
    int h0 = (oh + 1) & 1;
    int ihp0 = ((oh + 1 - h0) >> 1) + 1;
    const ushort_t* gsrc = d1 + (size_t)(b * 130 + ihp0 - 1) * 130 * 128;
    int sl = lane ^ ((lane >> 3) & 7);
    for (int u = wv; u < 65; u += 4)
        stage16(gsrc + (size_t)u * 512 + sl * 8, sm + u * 512);
    __syncthreads();

    int pw = wv & 1, mg = wv >> 1;
    int q0 = 1 - pw;
    fx4 acc[4][4];
    #pragma unroll
    for (int i = 0; i < 4; ++i)
        #pragma unroll
        for (int j = 0; j < 4; ++j) acc[i][j] = (fx4){0.f, 0.f, 0.f, 0.f};
    #pragma unroll
    for (int t2 = 0; t2 < 2; ++t2) {
        int kh = h0 + 2 * t2;
        int lrow = 1 - t2;
        #pragma unroll
        for (int t3 = 0; t3 < 2; ++t3) {
            int kw = q0 + 2 * t3;
            int cadd = pw + (t3 == 0 ? 1 : 0);
            int tap = kh * 4 + kw;
            #pragma unroll
            for (int ks = 0; ks < 4; ++ks) {
                bf16x8 bfr[4], af[4];
                #pragma unroll
                for (int nt = 0; nt < 4; ++nt)
                    bfr[nt] = *(const bf16x8*)(wr + ((size_t)(nt * 64 + tap * 4 + ks) * 64 + lane) * 8);
                #pragma unroll
                for (int mt = 0; mt < 4; ++mt) {
                    int px = cadd + (mg * 4 + mt) * 16 + n16;      // 0..129
                    af[mt] = sld(sm, (lrow * 130 + px) * 16 + ks * 4 + quad);
                }
                #pragma unroll
                for (int mt = 0; mt < 4; ++mt)
                    #pragma unroll
                    for (int nt = 0; nt < 4; ++nt)
                        acc[mt][nt] = MFMA16(af[mt], bfr[nt], acc[mt][nt]);
            }
        }
    }
    #pragma unroll
    for (int nt = 0; nt < 4; ++nt) {
        int co = nt * 16 + n16;
        float bs = bias[co];
        #pragma unroll
        for (int mt = 0; mt < 4; ++mt) {
            #pragma unroll
            for (int r = 0; r < 4; ++r) {
                int ow = 2 * ((mg * 4 + mt) * 16 + quad * 4 + r) + pw;
                d2[((size_t)(b * 258 + oh + 1) * 258 + (ow + 1)) * 64 + co] =
                    f2bf(fmaxf(acc[mt][nt][r] + bs, 0.f));
            }
        }
    }
}

// ------------------------- deconv3 MFMA -------------------------------------
// d2c -> out chunk (8,3,256,256) f32 sigmoid. Block=(b,oh,half): stage 3
// windows of 136px (17 chunks each). M=128, N=16(3 used). Wave: 2mt.
__global__ __launch_bounds__(256) void deconv3_mfma(
    const ushort_t* __restrict__ d2, const ushort_t* __restrict__ wr,
    const float* __restrict__ bias, float* __restrict__ out)
{
    __shared__ ushort_t sm[26112];          // 3 x 1088 slots
    int tid = threadIdx.x;
    int wv = tid >> 6, lane = tid & 63;
    int n16 = lane & 15, quad = lane >> 4;
    int blk = blockIdx.x;                   // 4096
    int half = blk & 1;
    int oh = (blk >> 1) & 255;
    int b = blk >> 9;
    int sl = lane ^ ((lane >> 3) & 7);
    for (int u = wv; u < 51; u += 4) {
        int c = u / 17, uu = u - c * 17;
        const ushort_t* gsrc = d2 + ((size_t)(b * 258 + oh + c) * 258 + half * 128) * 64;
        stage16(gsrc + (size_t)uu * 512 + sl * 8, sm + c * 8704 + uu * 512);
    }
    __syncthreads();

    fx4 acc[2];
    #pragma unroll
    for (int i = 0; i < 2; ++i) acc[i] = (fx4){0.f, 0.f, 0.f, 0.f};
    for (int tap = 0; tap < 9; ++tap) {
        int kh = tap / 3, kw = tap % 3;
        int c = 2 - kh;
        #pragma unroll
        for (int ks = 0; ks < 2; ++ks) {
            bf16x8 bfr = *(const bf16x8*)(wr + ((size_t)(tap * 2 + ks) * 64 + lane) * 8);
            bf16x8 af[2];
            #pragma unroll
            for (int mt = 0; mt < 2; ++mt) {
                int px = (2 - kw) + (wv * 2 + mt) * 16 + n16;      // 0..129
                af[mt] = sld(sm, c * 1088 + px * 8 + ks * 4 + quad);
            }
            #pragma unroll
            for (int mt = 0; mt < 2; ++mt)
                acc[mt] = MFMA16(af[mt], bfr, acc[mt]);
        }
    }
    int co = n16;
    if (co < 3) {
        float bs = bias[co];
        #pragma unroll
        for (int mt = 0; mt < 2; ++mt) {
            int ow0 = half * 128 + (wv * 2 + mt) * 16 + quad * 4;
            float4 v;
            v.x = 1.f / (1.f + __expf(-(acc[mt][0] + bs)));
            v.y = 1.f / (1.f + __expf(-(acc[mt][1] + bs)));
            v.z = 1.f / (1.f + __expf(-(acc[mt][2] + bs)));
            v.w = 1.f / (1.f + __expf(-(acc[mt][3] + bs)));
            *(float4*)(out + (((size_t)b * 3 + co) * 256 + oh) * 256 + ow0) = v;
        }
    }
}

// ---------------------------------------------------------------------------
extern "C" void kernel_launch(void* const* d_in, const int* in_sizes, int n_in,
                              void* d_out, int out_size, void* d_ws, size_t ws_size,
                              hipStream_t stream)
{
    const float* x   = (const float*)d_in[0];
    const float* w1  = (const float*)d_in[1];
    const float* b1  = (const float*)d_in[2];
    const float* w2  = (const float*)d_in[3];
    const float* b2  = (const float*)d_in[4];
    const float* w3  = (const float*)d_in[5];
    const float* b3  = (const float*)d_in[6];
    const float* emb = (const float*)d_in[7];
    const float* dw1 = (const float*)d_in[8];
    const float* db1 = (const float*)d_in[9];
    const float* dw2 = (const float*)d_in[10];
    const float* db2 = (const float*)d_in[11];
    const float* dw3 = (const float*)d_in[12];
    const float* db3 = (const float*)d_in[13];
    float* xout = (float*)d_out;

    ushort_t* xp   = (ushort_t*)d_ws;            // 32*130*130*64 = 34,611,200
    ushort_t* h2p  = xp   + 34611200;            // 32*66*66*128  = 17,842,176
    ushort_t* qpad = h2p  + 17842176;            // 32*66*66*64   =  8,921,088
    ushort_t* d1c  = qpad + 8921088;             //  8*130*130*128= 17,305,600
    ushort_t* d2c  = d1c  + 17305600;            //  8*258*258*64 = 34,080,768
    ushort_t* zb   = d2c  + 34080768;            // 32*64*64*64   =  8,388,608
    ushort_t* wr1  = zb   + 8388608;             //   4,096
    ushort_t* wr2  = wr1  + 4096;                // 131,072
    ushort_t* wr3  = wr2  + 131072;              //  73,728
    ushort_t* wd1  = wr3  + 73728;               // 131,072
    ushort_t* wd2  = wd1  + 131072;              // 131,072
    ushort_t* wd3  = wd2  + 131072;              //   9,216
    float*    lac  = (float*)(wd3 + 9216);
    // x4 [32][258][258][4] = 8,520,192 aliases d2c (decoder-only region,
    // used before the decoder loop; halo_zero(d2c) runs AFTER conv1_mfma).
    ushort_t* x4   = d2c;

    x4_halo<<<129, 256, 0, stream>>>(x4);
    cast_x4<<<8192, 256, 0, stream>>>(x, x4);

    repack_w1<<<16,  256, 0, stream>>>(w1, wr1);
    repack_w2<<<512, 256, 0, stream>>>(w2, wr2);
    repack_w3<<<288, 256, 0, stream>>>(w3, wr3);
    repack_d1<<<512, 256, 0, stream>>>(dw1, wd1);
    repack_d2<<<512, 256, 0, stream>>>(dw2, wd2);
    repack_d3<<<36,  256, 0, stream>>>(dw3, wd3);

    halo_zero<<<516, 256, 0, stream>>>(xp,   32, 130, 130, 8);
    halo_zero<<<520, 256, 0, stream>>>(h2p,  32,  66,  66, 16);
    halo_zero<<<260, 256, 0, stream>>>(qpad, 32,  66,  66, 8);
    zero_k<<<1, 1, 0, stream>>>(lac);

    conv1_mfma<<<4096, 256, 0, stream>>>(x4, wr1, b1, xp);
    conv2_mfma<<<2048, 256, 0, stream>>>(xp, wr2, b2, h2p);
    conv3_mfma<<<2048, 256, 0, stream>>>(h2p, wr3, b3, zb);
    vq_k      <<<512,  256, 0, stream>>>(zb, emb, qpad, lac);
    loss_fin_k<<<1, 1, 0, stream>>>(lac, xout + 6291456);

    halo_zero<<<258, 256, 0, stream>>>(d1c, 8, 130, 130, 16);
    halo_zero<<<257, 256, 0, stream>>>(d2c, 8, 258, 258, 8);

    for (int c0 = 0; c0 < 32; c0 += 8) {
        deconv1_mfma<<<1024, 256, 0, stream>>>(qpad + (size_t)c0 * 278784, wd1, db1, d1c);
        deconv2_mfma<<<2048, 256, 0, stream>>>(d1c, wd2, db2, d2c);
        deconv3_mfma<<<4096, 256, 0, stream>>>(d2c, wd3, db3, xout + (size_t)c0 * 196608);
    }
}

// Round 7
// 728.185 us; speedup vs baseline: 20.8219x; 1.2257x over previous
//
#include <hip/hip_runtime.h>
#include <math.h>

// ---------------------------------------------------------------------------
// VQ-VAE forward, round 6.
// vs round 5: (1) VQ rewritten as MFMA GEMM [pos x 64] @ [64 x 512] with
// z staged in LDS and emb pre-cast to bf16 B-frag layout; running argmin in
// registers, cross-lane (score,idx) min via shfl_xor (first-min tie-break).
// (2) setup launches fused: repack_all (weights+emb+|e|^2+lac), halo3/halo2,
// x4 halo folded into cast_x4. 13 setup launches -> 4.
// MFMA 16x16x32 layouts (m89): A/B frag row=lane&15, k=(lane>>4)*8+j.
// C/D: col(n)=lane&15, row(m)=(lane>>4)*4+reg.
// ---------------------------------------------------------------------------

typedef __attribute__((ext_vector_type(8))) short bf16x8;
typedef __attribute__((ext_vector_type(4))) float fx4;
typedef unsigned short ushort_t;
#define MFMA16(a, b, c) __builtin_amdgcn_mfma_f32_16x16x32_bf16(a, b, c, 0, 0, 0)

__device__ inline ushort_t f2bf(float f) {
    unsigned u = __float_as_uint(f);
    u += 0x7FFFu + ((u >> 16) & 1u);
    return (ushort_t)(u >> 16);
}
__device__ inline float bf2f(ushort_t h) {
    return __uint_as_float(((unsigned)h) << 16);
}

// async global->LDS 16B per lane: g per-lane, l wave-uniform (lane i -> l+i*16)
__device__ __forceinline__ void stage16(const ushort_t* g, ushort_t* l) {
#if __has_builtin(__builtin_amdgcn_global_load_lds)
    __builtin_amdgcn_global_load_lds(
        (const __attribute__((address_space(1))) unsigned int*)g,
        (__attribute__((address_space(3))) unsigned int*)l, 16, 0, 0);
#else
    int lane = threadIdx.x & 63;
    *(int4*)(l + lane * 8) = *(const int4*)g;
#endif
}

// XOR swizzle over 16B slots (self-inverse), chunk-local (64 slots).
__device__ __forceinline__ int swz(int s) { return s ^ ((s >> 3) & 7); }
__device__ __forceinline__ bf16x8 sld(const ushort_t* sm, int gslot) {
    return *(const bf16x8*)(sm + (size_t)swz(gslot) * 8);
}

// zero one 16B halo element of [B][H][W][C8*8] buffer
__device__ __forceinline__ void halo_do(
    ushort_t* __restrict__ buf, int B, int H, int W, int C8, int idx)
{
    int perim = 2 * W + 2 * (H - 2);
    int c8 = idx % C8;
    int t = idx / C8;
    int p = t % perim;
    int b = t / perim;
    int r, col;
    if (p < W) { r = 0; col = p; }
    else if (p < 2 * W) { r = H - 1; col = p - W; }
    else { int pp = p - 2 * W; r = 1 + (pp >> 1); col = (pp & 1) ? (W - 1) : 0; }
    size_t off = ((((size_t)b * H + r) * W + col) * C8 + c8) * 8;
    *(int4*)(buf + off) = (int4){0, 0, 0, 0};
}

// halos for encoder-side buffers
__global__ __launch_bounds__(256) void halo3_k(
    ushort_t* __restrict__ xp, ushort_t* __restrict__ h2p, ushort_t* __restrict__ qpad)
{
    int i = blockIdx.x * 256 + threadIdx.x;
    if (i < 132096) halo_do(xp, 32, 130, 130, 8, i);
    else if (i < 265216) halo_do(h2p, 32, 66, 66, 16, i - 132096);
    else if (i < 331776) halo_do(qpad, 32, 66, 66, 8, i - 265216);
}
// halos for decoder-side buffers (must run after conv1: x4 aliases d2c)
__global__ __launch_bounds__(256) void halo2_k(
    ushort_t* __restrict__ d1c, ushort_t* __restrict__ d2c)
{
    int i = blockIdx.x * 256 + threadIdx.x;
    if (i < 66048) halo_do(d1c, 8, 130, 130, 16, i);
    else if (i < 131840) halo_do(d2c, 8, 258, 258, 8, i - 66048);
}

// x (32,3,256,256) f32 -> x4 [32][258][258][4] bf16 (ci=3 zero); + halo zero
__global__ __launch_bounds__(256) void cast_x4(
    const float* __restrict__ x, ushort_t* __restrict__ x4)
{
    if (blockIdx.x < 8192) {
        int i = blockIdx.x * 256 + threadIdx.x;   // 2,097,152
        int w = i & 255, h = (i >> 8) & 255, b = i >> 16;
        size_t base = ((size_t)b * 3 * 256 + h) * 256 + w;
        float v0 = x[base];
        float v1 = x[base + 65536];
        float v2 = x[base + 131072];
        uint2 o;
        o.x = (unsigned)f2bf(v0) | ((unsigned)f2bf(v1) << 16);
        o.y = (unsigned)f2bf(v2);
        *(uint2*)(x4 + ((size_t)(b * 258 + h + 1) * 258 + (w + 1)) * 4) = o;
    } else {
        int idx = (blockIdx.x - 8192) * 256 + threadIdx.x;
        if (idx >= 32 * 1032) return;
        int b = idx / 1032;
        int s = idx % 1032;
        int side = s / 258, c = s % 258;
        int r, col;
        if (side == 0) { r = 0; col = c; }
        else if (side == 1) { r = 257; col = c; }
        else if (side == 2) { r = c; col = 0; }
        else { r = c; col = 257; }
        *(uint2*)(x4 + ((size_t)(b * 258 + r) * 258 + col) * 4) = (uint2){0, 0};
    }
}

// ---------------- fused repack: all weights + embb + se2 + lac --------------
// swizzled weight layout: off = ((t*numC + c)*64 + lane)*8 + j ;
// co = t*16 + (lane&15); k = c*32 + (lane>>4)*8 + j
__global__ __launch_bounds__(256) void repack_all(
    const float* __restrict__ w1, const float* __restrict__ w2,
    const float* __restrict__ w3, const float* __restrict__ dw1,
    const float* __restrict__ dw2, const float* __restrict__ dw3,
    const float* __restrict__ emb,
    ushort_t* __restrict__ o1, ushort_t* __restrict__ o2,
    ushort_t* __restrict__ o3, ushort_t* __restrict__ od1,
    ushort_t* __restrict__ od2, ushort_t* __restrict__ od3,
    ushort_t* __restrict__ embb, float* __restrict__ se2,
    float* __restrict__ lac)
{
    int gi = blockIdx.x * 256 + threadIdx.x;
    if (gi < 4096) {                         // w1 [64co][3ci][4][4]
        int i = gi;
        int j = i & 7, lane = (i >> 3) & 63, tc = i >> 9;
        int c = tc & 1, t = tc >> 1;
        int co = t * 16 + (lane & 15);
        int k = c * 32 + (lane >> 4) * 8 + j;
        int kh = k >> 4, kw = (k >> 2) & 3, ci = k & 3;
        o1[i] = (ci < 3) ? f2bf(w1[((co * 3 + ci) * 4 + kh) * 4 + kw]) : (ushort_t)0;
    } else if (gi < 135168) {                // w2 [128co][64ci][4][4], numC=32
        int i = gi - 4096;
        int j = i & 7, lane = (i >> 3) & 63, tc = i >> 9;
        int c = tc & 31, t = tc >> 5;
        int co = t * 16 + (lane & 15);
        int k = c * 32 + (lane >> 4) * 8 + j;
        int tap = k >> 6, ci = k & 63, kh = tap >> 2, kw = tap & 3;
        o2[i] = f2bf(w2[((co * 64 + ci) * 4 + kh) * 4 + kw]);
    } else if (gi < 208896) {                // w3 [64co][128ci][3][3], numC=36
        int i = gi - 135168;
        int j = i & 7, lane = (i >> 3) & 63, tc = i >> 9;
        int c = tc % 36, t = tc / 36;
        int co = t * 16 + (lane & 15);
        int k = c * 32 + (lane >> 4) * 8 + j;
        int tap = k >> 7, ci = k & 127, kh = tap / 3, kw = tap % 3;
        o3[i] = f2bf(w3[((co * 128 + ci) * 3 + kh) * 3 + kw]);
    } else if (gi < 339968) {                // dw1 [64ci][128co][4][4], numC=32
        int i = gi - 208896;
        int j = i & 7, lane = (i >> 3) & 63, tc = i >> 9;
        int c = tc & 31, t = tc >> 5;
        int co = t * 16 + (lane & 15);
        int k = c * 32 + (lane >> 4) * 8 + j;
        int tap = k >> 6, ci = k & 63, kh = tap >> 2, kw = tap & 3;
        od1[i] = f2bf(dw1[((ci * 128 + co) * 4 + kh) * 4 + kw]);
    } else if (gi < 471040) {                // dw2 [128ci][64co][4][4], numC=64
        int i = gi - 339968;
        int j = i & 7, lane = (i >> 3) & 63, tc = i >> 9;
        int c = tc & 63, t = tc >> 6;
        int co = t * 16 + (lane & 15);
        int k = c * 32 + (lane >> 4) * 8 + j;
        int tap = k >> 7, ci = k & 127, kh = tap >> 2, kw = tap & 3;
        od2[i] = f2bf(dw2[((ci * 64 + co) * 4 + kh) * 4 + kw]);
    } else if (gi < 480256) {                // dw3 [64ci][3co][3][3], numC=18
        int i = gi - 471040;
        int j = i & 7, lane = (i >> 3) & 63, c = i >> 9;
        int co = lane & 15;
        int k = c * 32 + (lane >> 4) * 8 + j;
        int tap = k >> 6, ci = k & 63, kh = tap / 3, kw = tap % 3;
        od3[i] = (co < 3) ? f2bf(dw3[((ci * 3 + co) * 3 + kh) * 3 + kw]) : (ushort_t)0;
    } else if (gi < 513024) {                // embb [512n][64k] B-frag layout
        int i = gi - 480256;
        int j = i & 7, lane = (i >> 3) & 63, c = (i >> 9) & 1, nt = i >> 10;
        int n = nt * 16 + (lane & 15);
        int k = c * 32 + (lane >> 4) * 8 + j;
        embb[i] = f2bf(emb[n * 64 + k]);
    } else if (gi < 513536) {                // se2[512] fp32 |e|^2
        int n = gi - 513024;
        const float* e = emb + n * 64;
        float s = 0.f;
        for (int d = 0; d < 64; ++d) s = fmaf(e[d], e[d], s);
        se2[n] = s;
    } else if (gi == 513536) {
        lac[0] = 0.f;
    }
}

// ------------------------- conv1 MFMA ---------------------------------------
__global__ __launch_bounds__(256) void conv1_mfma(
    const ushort_t* __restrict__ x4, const ushort_t* __restrict__ wr,
    const float* __restrict__ bias, ushort_t* __restrict__ xp)
{
    __shared__ ushort_t sm[4608];
    int tid = threadIdx.x;
    int wv = tid >> 6, lane = tid & 63;
    int n16 = lane & 15, quad = lane >> 4;
    int blk = blockIdx.x;                   // 4096
    int oh = blk & 127, b = blk >> 7;
    const ushort_t* gsrc = x4 + (size_t)(b * 258 + 2 * oh) * 1032;
    int sl = lane ^ ((lane >> 3) & 7);
    for (int u = wv; u < 9; u += 4)
        stage16(gsrc + u * 512 + sl * 8, sm + u * 512);
    __syncthreads();

    fx4 acc[2][4];
    #pragma unroll
    for (int i = 0; i < 2; ++i)
        #pragma unroll
        for (int j = 0; j < 4; ++j) acc[i][j] = (fx4){0.f, 0.f, 0.f, 0.f};
    #pragma unroll
    for (int c = 0; c < 2; ++c) {
        int kh = 2 * c + (quad >> 1);
        int kwh = quad & 1;
        bf16x8 af[2], bfr[4];
        #pragma unroll
        for (int mt = 0; mt < 2; ++mt) {
            int ow = (wv * 2 + mt) * 16 + n16;
            af[mt] = sld(sm, kh * 129 + ow + kwh);
        }
        #pragma unroll
        for (int nt = 0; nt < 4; ++nt)
            bfr[nt] = *(const bf16x8*)(wr + ((size_t)(nt * 2 + c) * 64 + lane) * 8);
        #pragma unroll
        for (int mt = 0; mt < 2; ++mt)
            #pragma unroll
            for (int nt = 0; nt < 4; ++nt)
                acc[mt][nt] = MFMA16(af[mt], bfr[nt], acc[mt][nt]);
    }
    #pragma unroll
    for (int nt = 0; nt < 4; ++nt) {
        int co = nt * 16 + n16;
        float bs = bias[co];
        #pragma unroll
        for (int mt = 0; mt < 2; ++mt) {
            #pragma unroll
            for (int r = 0; r < 4; ++r) {
                int ow = (wv * 2 + mt) * 16 + quad * 4 + r;
                xp[((size_t)(b * 130 + oh + 1) * 130 + (ow + 1)) * 64 + co] =
                    f2bf(fmaxf(acc[mt][nt][r] + bs, 0.f));
            }
        }
    }
}

// ------------------------- conv2 MFMA ---------------------------------------
__global__ __launch_bounds__(256) void conv2_mfma(
    const ushort_t* __restrict__ xp, const ushort_t* __restrict__ wr,
    const float* __restrict__ bias, ushort_t* __restrict__ h2p)
{
    __shared__ ushort_t sm[33280];
    int tid = threadIdx.x;
    int wv = tid >> 6, lane = tid & 63;
    int n16 = lane & 15, quad = lane >> 4;
    int blk = blockIdx.x;                   // 2048
    int oh = blk & 63, b = blk >> 6;
    const ushort_t* gsrc = xp + (size_t)(b * 130 + 2 * oh) * 130 * 64;
    int sl = lane ^ ((lane >> 3) & 7);
    for (int u = wv; u < 65; u += 4)
        stage16(gsrc + (size_t)u * 512 + sl * 8, sm + u * 512);
    __syncthreads();

    int mg = wv & 1, ng = wv >> 1;
    fx4 acc[2][4];
    #pragma unroll
    for (int i = 0; i < 2; ++i)
        #pragma unroll
        for (int j = 0; j < 4; ++j) acc[i][j] = (fx4){0.f, 0.f, 0.f, 0.f};
    for (int tap = 0; tap < 16; ++tap) {
        int kh = tap >> 2, kw = tap & 3;
        #pragma unroll
        for (int ks = 0; ks < 2; ++ks) {
            bf16x8 bfr[4], af[2];
            #pragma unroll
            for (int nt = 0; nt < 4; ++nt)
                bfr[nt] = *(const bf16x8*)(wr + ((size_t)((ng * 4 + nt) * 32 + tap * 2 + ks) * 64 + lane) * 8);
            #pragma unroll
            for (int mt = 0; mt < 2; ++mt) {
                int px = kw + 2 * ((mg * 2 + mt) * 16 + n16);      // 0..129
                af[mt] = sld(sm, (kh * 130 + px) * 8 + ks * 4 + quad);
            }
            #pragma unroll
            for (int mt = 0; mt < 2; ++mt)
                #pragma unroll
                for (int nt = 0; nt < 4; ++nt)
                    acc[mt][nt] = MFMA16(af[mt], bfr[nt], acc[mt][nt]);
        }
    }
    #pragma unroll
    for (int nt = 0; nt < 4; ++nt) {
        int co = (ng * 4 + nt) * 16 + n16;
        float bs = bias[co];
        #pragma unroll
        for (int mt = 0; mt < 2; ++mt) {
            #pragma unroll
            for (int r = 0; r < 4; ++r) {
                int ow = (mg * 2 + mt) * 16 + quad * 4 + r;
                h2p[((size_t)(b * 66 + oh + 1) * 66 + (ow + 1)) * 128 + co] =
                    f2bf(fmaxf(acc[mt][nt][r] + bs, 0.f));
            }
        }
    }
}

// ------------------------- conv3 MFMA ---------------------------------------
__global__ __launch_bounds__(256) void conv3_mfma(
    const ushort_t* __restrict__ hp, const ushort_t* __restrict__ wr,
    const float* __restrict__ bias, ushort_t* __restrict__ z)
{
    __shared__ ushort_t sm[25600];
    int tid = threadIdx.x;
    int wv = tid >> 6, lane = tid & 63;
    int n16 = lane & 15, quad = lane >> 4;
    int blk = blockIdx.x;                   // 2048
    int oh = blk & 63, b = blk >> 6;
    const ushort_t* gsrc = hp + (size_t)(b * 66 + oh) * 66 * 128;
    int sl = lane ^ ((lane >> 3) & 7);
    for (int u = wv; u < 50; u += 4)
        stage16(gsrc + (size_t)u * 512 + sl * 8, sm + u * 512);
    __syncthreads();

    int mg = wv & 1, ng = wv >> 1;
    fx4 acc[2][2];
    #pragma unroll
    for (int i = 0; i < 2; ++i)
        #pragma unroll
        for (int j = 0; j < 2; ++j) acc[i][j] = (fx4){0.f, 0.f, 0.f, 0.f};
    for (int tap = 0; tap < 9; ++tap) {
        int kh = tap / 3, kw = tap % 3;
        #pragma unroll
        for (int ks = 0; ks < 4; ++ks) {
            bf16x8 bfr[2], af[2];
            #pragma unroll
            for (int nt = 0; nt < 2; ++nt)
                bfr[nt] = *(const bf16x8*)(wr + ((size_t)((ng * 2 + nt) * 36 + tap * 4 + ks) * 64 + lane) * 8);
            #pragma unroll
            for (int mt = 0; mt < 2; ++mt) {
                int px = kw + (mg * 2 + mt) * 16 + n16;            // 0..65
                af[mt] = sld(sm, (kh * 66 + px) * 16 + ks * 4 + quad);
            }
            #pragma unroll
            for (int mt = 0; mt < 2; ++mt)
                #pragma unroll
                for (int nt = 0; nt < 2; ++nt)
                    acc[mt][nt] = MFMA16(af[mt], bfr[nt], acc[mt][nt]);
        }
    }
    #pragma unroll
    for (int nt = 0; nt < 2; ++nt) {
        int co = (ng * 2 + nt) * 16 + n16;
        float bs = bias[co];
        #pragma unroll
        for (int mt = 0; mt < 2; ++mt) {
            #pragma unroll
            for (int r = 0; r < 4; ++r) {
                int ow = (mg * 2 + mt) * 16 + quad * 4 + r;
                z[((size_t)(b * 64 + oh) * 64 + ow) * 64 + co] =
                    f2bf(fmaxf(acc[mt][nt][r] + bs, 0.f));
            }
        }
    }
}

// ------------------------- VQ MFMA ------------------------------------------
// z NHWC [pos][64] -> argmin over 512 codes via MFMA; q to qpad; loss atomic.
// Block: 256 positions (4 waves x 64). A = z rows (LDS), B = embb tiles.
__global__ __launch_bounds__(256) void vq_mfma(
    const ushort_t* __restrict__ z, const ushort_t* __restrict__ embb,
    const float* __restrict__ emb, const float* __restrict__ se2g,
    ushort_t* __restrict__ qpad, float* __restrict__ loss_acc)
{
    __shared__ ushort_t smz[16384];         // 256 x 64 bf16 (swizzled)
    __shared__ float sse2[512];
    __shared__ float red[256];
    int tid = threadIdx.x;
    int wv = tid >> 6, lane = tid & 63;
    int n16 = lane & 15, quad = lane >> 4;
    int blk = blockIdx.x;                   // 512
    const ushort_t* gsrc = z + (size_t)blk * 16384;
    int sl = lane ^ ((lane >> 3) & 7);
    for (int u = wv; u < 32; u += 4)
        stage16(gsrc + (size_t)u * 512 + sl * 8, smz + u * 512);
    for (int i = tid; i < 512; i += 256) sse2[i] = se2g[i];
    __syncthreads();

    // A-frags: 64 positions per wave (rows m = wv*64 + mt*16 + n16)
    bf16x8 a[4][2];
    #pragma unroll
    for (int mt = 0; mt < 4; ++mt)
        #pragma unroll
        for (int ks = 0; ks < 2; ++ks)
            a[mt][ks] = sld(smz, (wv * 64 + mt * 16 + n16) * 8 + ks * 4 + quad);

    float best[4][4];
    int bid[4][4];
    #pragma unroll
    for (int mt = 0; mt < 4; ++mt)
        #pragma unroll
        for (int r = 0; r < 4; ++r) { best[mt][r] = 1e30f; bid[mt][r] = 0; }

    for (int nt = 0; nt < 32; ++nt) {
        bf16x8 b0 = *(const bf16x8*)(embb + ((size_t)(nt * 2 + 0) * 64 + lane) * 8);
        bf16x8 b1 = *(const bf16x8*)(embb + ((size_t)(nt * 2 + 1) * 64 + lane) * 8);
        float s2 = sse2[nt * 16 + n16];
        int myn = nt * 16 + n16;
        #pragma unroll
        for (int mt = 0; mt < 4; ++mt) {
            fx4 acc = (fx4){0.f, 0.f, 0.f, 0.f};
            acc = MFMA16(a[mt][0], b0, acc);
            acc = MFMA16(a[mt][1], b1, acc);
            #pragma unroll
            for (int r = 0; r < 4; ++r) {
                float sc = fmaf(-2.f, acc[r], s2);
                if (sc < best[mt][r]) { best[mt][r] = sc; bid[mt][r] = myn; }
            }
        }
    }

    float lsum = 0.f;
    #pragma unroll
    for (int mt = 0; mt < 4; ++mt) {
        #pragma unroll
        for (int r = 0; r < 4; ++r) {
            float bs = best[mt][r];
            int bi = bid[mt][r];
            #pragma unroll
            for (int st = 1; st < 16; st <<= 1) {
                float os = __shfl_xor(bs, st, 64);
                int oi = __shfl_xor(bi, st, 64);
                if (os < bs || (os == bs && oi < bi)) { bs = os; bi = oi; }
            }
            // row = wv*64 + mt*16 + quad*4 + r ; all 16 lanes of quad agree on bi
            int ml = wv * 64 + mt * 16 + quad * 4 + r;
            int pos = blk * 256 + ml;
            int b = pos >> 12, h = (pos >> 6) & 63, w = pos & 63;
            float4 ev = *(const float4*)(emb + (size_t)bi * 64 + n16 * 4);
            int slot = ml * 8 + (n16 >> 1);
            const ushort_t* zp = smz + (size_t)swz(slot) * 8 + (n16 & 1) * 4;
            float d0 = ev.x - bf2f(zp[0]);
            float d1 = ev.y - bf2f(zp[1]);
            float d2 = ev.z - bf2f(zp[2]);
            float d3 = ev.w - bf2f(zp[3]);
            lsum = fmaf(d0, d0, lsum);
            lsum = fmaf(d1, d1, lsum);
            lsum = fmaf(d2, d2, lsum);
            lsum = fmaf(d3, d3, lsum);
            uint2 o;
            o.x = (unsigned)f2bf(ev.x) | ((unsigned)f2bf(ev.y) << 16);
            o.y = (unsigned)f2bf(ev.z) | ((unsigned)f2bf(ev.w) << 16);
            *(uint2*)(qpad + ((size_t)(b * 66 + h + 1) * 66 + (w + 1)) * 64 + n16 * 4) = o;
        }
    }
    red[tid] = lsum;
    __syncthreads();
    for (int s = 128; s > 0; s >>= 1) {
        if (tid < s) red[tid] += red[tid + s];
        __syncthreads();
    }
    if (tid == 0) atomicAdd(loss_acc, red[0]);
}

__global__ void loss_fin_k(const float* __restrict__ acc, float* __restrict__ out)
{
    out[0] = 1.25f * acc[0] / 8388608.0f;
}

// ------------------------- deconv1 MFMA -------------------------------------
__global__ __launch_bounds__(256) void deconv1_mfma(
    const ushort_t* __restrict__ q, const ushort_t* __restrict__ wr,
    const float* __restrict__ bias, ushort_t* __restrict__ d1)
{
    __shared__ ushort_t sm[8704];
    int tid = threadIdx.x;
    int wv = tid >> 6, lane = tid & 63;
    int n16 = lane & 15, quad = lane >> 4;
    int blk = blockIdx.x;                   // 1024
    int oh = blk & 127, b = blk >> 7;
    int h0 = (oh + 1) & 1;
    int ihp0 = ((oh + 1 - h0) >> 1) + 1;
    const ushort_t* gsrc = q + (size_t)(b * 66 + ihp0 - 1) * 66 * 64;
    int sl = lane ^ ((lane >> 3) & 7);
    for (int u = wv; u < 17; u += 4)
        stage16(gsrc + (size_t)u * 512 + sl * 8, sm + u * 512);
    __syncthreads();

    int pw = wv & 1, mg = wv >> 1;
    int q0 = 1 - pw;
    fx4 acc[2][8];
    #pragma unroll
    for (int i = 0; i < 2; ++i)
        #pragma unroll
        for (int j = 0; j < 8; ++j) acc[i][j] = (fx4){0.f, 0.f, 0.f, 0.f};
    #pragma unroll
    for (int t2 = 0; t2 < 2; ++t2) {
        int kh = h0 + 2 * t2;
        int lrow = 1 - t2;
        #pragma unroll
        for (int t3 = 0; t3 < 2; ++t3) {
            int kw = q0 + 2 * t3;
            int cadd = pw + (t3 == 0 ? 1 : 0);
            int tap = kh * 4 + kw;
            #pragma unroll
            for (int ks = 0; ks < 2; ++ks) {
                bf16x8 bfr[8], af[2];
                #pragma unroll
                for (int nt = 0; nt < 8; ++nt)
                    bfr[nt] = *(const bf16x8*)(wr + ((size_t)(nt * 32 + tap * 2 + ks) * 64 + lane) * 8);
                #pragma unroll
                for (int mt = 0; mt < 2; ++mt) {
                    int px = cadd + (mg * 2 + mt) * 16 + n16;      // 0..65
                    af[mt] = sld(sm, (lrow * 66 + px) * 8 + ks * 4 + quad);
                }
                #pragma unroll
                for (int mt = 0; mt < 2; ++mt)
                    #pragma unroll
                    for (int nt = 0; nt < 8; ++nt)
                        acc[mt][nt] = MFMA16(af[mt], bfr[nt], acc[mt][nt]);
            }
        }
    }
    #pragma unroll
    for (int nt = 0; nt < 8; ++nt) {
        int co = nt * 16 + n16;
        float bs = bias[co];
        #pragma unroll
        for (int mt = 0; mt < 2; ++mt) {
            #pragma unroll
            for (int r = 0; r < 4; ++r) {
                int ow = 2 * ((mg * 2 + mt) * 16 + quad * 4 + r) + pw;
                d1[((size_t)(b * 130 + oh + 1) * 130 + (ow + 1)) * 128 + co] =
                    f2bf(fmaxf(acc[mt][nt][r] + bs, 0.f));
            }
        }
    }
}

// ------------------------- deconv2 MFMA -------------------------------------
__global__ __launch_bounds__(256) void deconv2_mfma(
    const ushort_t* __restrict__ d1, const ushort_t* __restrict__ wr,
    const float* __restrict__ bias, ushort_t* __restrict__ d2)
{
    __shared__ ushort_t sm[33280];
    int tid = threadIdx.x;
    int wv = tid >> 6, lane = tid & 63;
    int n16 = lane & 15, quad = lane >> 4;
    int blk = blockIdx.x;                   // 2048
    int oh = blk & 255, b = blk >> 8;
    int h0 = (oh + 1) & 1;
    int ihp0 = ((oh + 1 - h0) >> 1) + 1;
    const ushort_t* gsrc = d1 + (size_t)(b * 130 + ihp0 - 1) * 130 * 128;
    int sl = lane ^ ((lane >> 3) & 7);
    for (int u = wv; u < 65; u += 4)
        stage16(gsrc + (size_t)u * 512 + sl * 8, sm + u * 512);
    __syncthreads();

    int pw = wv & 1, mg = wv >> 1;
    int q0 = 1 - pw;
    fx4 acc[4][4];
    #pragma unroll
    for (int i = 0; i < 4; ++i)
        #pragma unroll
        for (int j = 0; j < 4; ++j) acc[i][j] = (fx4){0.f, 0.f, 0.f, 0.f};
    #pragma unroll
    for (int t2 = 0; t2 < 2; ++t2) {
        int kh = h0 + 2 * t2;
        int lrow = 1 - t2;
        #pragma unroll
        for (int t3 = 0; t3 < 2; ++t3) {
            int kw = q0 + 2 * t3;
            int cadd = pw + (t3 == 0 ? 1 : 0);
            int tap = kh * 4 + kw;
            #pragma unroll
            for (int ks = 0; ks < 4; ++ks) {
                bf16x8 bfr[4], af[4];
                #pragma unroll
                for (int nt = 0; nt < 4; ++nt)
                    bfr[nt] = *(const bf16x8*)(wr + ((size_t)(nt * 64 + tap * 4 + ks) * 64 + lane) * 8);
                #pragma unroll
                for (int mt = 0; mt < 4; ++mt) {
                    int px = cadd + (mg * 4 + mt) * 16 + n16;      // 0..129
                    af[mt] = sld(sm, (lrow * 130 + px) * 16 + ks * 4 + quad);
                }
                #pragma unroll
                for (int mt = 0; mt < 4; ++mt)
                    #pragma unroll
                    for (int nt = 0; nt < 4; ++nt)
                        acc[mt][nt] = MFMA16(af[mt], bfr[nt], acc[mt][nt]);
            }
        }
    }
    #pragma unroll
    for (int nt = 0; nt < 4; ++nt) {
        int co = nt * 16 + n16;
        float bs = bias[co];
        #pragma unroll
        for (int mt = 0; mt < 4; ++mt) {
            #pragma unroll
            for (int r = 0; r < 4; ++r) {
                int ow = 2 * ((mg * 4 + mt) * 16 + quad * 4 + r) + pw;
                d2[((size_t)(b * 258 + oh + 1) * 258 + (ow + 1)) * 64 + co] =
                    f2bf(fmaxf(acc[mt][nt][r] + bs, 0.f));
            }
        }
    }
}

// ------------------------- deconv3 MFMA -------------------------------------
__global__ __launch_bounds__(256) void deconv3_mfma(
    const ushort_t* __restrict__ d2, const ushort_t* __restrict__ wr,
    const float* __restrict__ bias, float* __restrict__ out)
{
    __shared__ ushort_t sm[26112];          // 3 x 1088 slots
    int tid = threadIdx.x;
    int wv = tid >> 6, lane = tid & 63;
    int n16 = lane & 15, quad = lane >> 4;
    int blk = blockIdx.x;                   // 4096
    int half = blk & 1;
    int oh = (blk >> 1) & 255;
    int b = blk >> 9;
    int sl = lane ^ ((lane >> 3) & 7);
    for (int u = wv; u < 51; u += 4) {
        int c = u / 17, uu = u - c * 17;
        const ushort_t* gsrc = d2 + ((size_t)(b * 258 + oh + c) * 258 + half * 128) * 64;
        stage16(gsrc + (size_t)uu * 512 + sl * 8, sm + c * 8704 + uu * 512);
    }
    __syncthreads();

    fx4 acc[2];
    #pragma unroll
    for (int i = 0; i < 2; ++i) acc[i] = (fx4){0.f, 0.f, 0.f, 0.f};
    for (int tap = 0; tap < 9; ++tap) {
        int kh = tap / 3, kw = tap % 3;
        int c = 2 - kh;
        #pragma unroll
        for (int ks = 0; ks < 2; ++ks) {
            bf16x8 bfr = *(const bf16x8*)(wr + ((size_t)(tap * 2 + ks) * 64 + lane) * 8);
            bf16x8 af[2];
            #pragma unroll
            for (int mt = 0; mt < 2; ++mt) {
                int px = (2 - kw) + (wv * 2 + mt) * 16 + n16;      // 0..129
                af[mt] = sld(sm, c * 1088 + px * 8 + ks * 4 + quad);
            }
            #pragma unroll
            for (int mt = 0; mt < 2; ++mt)
                acc[mt] = MFMA16(af[mt], bfr, acc[mt]);
        }
    }
    int co = n16;
    if (co < 3) {
        float bs = bias[co];
        #pragma unroll
        for (int mt = 0; mt < 2; ++mt) {
            int ow0 = half * 128 + (wv * 2 + mt) * 16 + quad * 4;
            float4 v;
            v.x = 1.f / (1.f + __expf(-(acc[mt][0] + bs)));
            v.y = 1.f / (1.f + __expf(-(acc[mt][1] + bs)));
            v.z = 1.f / (1.f + __expf(-(acc[mt][2] + bs)));
            v.w = 1.f / (1.f + __expf(-(acc[mt][3] + bs)));
            *(float4*)(out + (((size_t)b * 3 + co) * 256 + oh) * 256 + ow0) = v;
        }
    }
}

// ---------------------------------------------------------------------------
extern "C" void kernel_launch(void* const* d_in, const int* in_sizes, int n_in,
                              void* d_out, int out_size, void* d_ws, size_t ws_size,
                              hipStream_t stream)
{
    const float* x   = (const float*)d_in[0];
    const float* w1  = (const float*)d_in[1];
    const float* b1  = (const float*)d_in[2];
    const float* w2  = (const float*)d_in[3];
    const float* b2  = (const float*)d_in[4];
    const float* w3  = (const float*)d_in[5];
    const float* b3  = (const float*)d_in[6];
    const float* emb = (const float*)d_in[7];
    const float* dw1 = (const float*)d_in[8];
    const float* db1 = (const float*)d_in[9];
    const float* dw2 = (const float*)d_in[10];
    const float* db2 = (const float*)d_in[11];
    const float* dw3 = (const float*)d_in[12];
    const float* db3 = (const float*)d_in[13];
    float* xout = (float*)d_out;

    ushort_t* xp   = (ushort_t*)d_ws;            // 32*130*130*64 = 34,611,200
    ushort_t* h2p  = xp   + 34611200;            // 32*66*66*128  = 17,842,176
    ushort_t* qpad = h2p  + 17842176;            // 32*66*66*64   =  8,921,088
    ushort_t* d1c  = qpad + 8921088;             //  8*130*130*128= 17,305,600
    ushort_t* d2c  = d1c  + 17305600;            //  8*258*258*64 = 34,080,768
    ushort_t* zb   = d2c  + 34080768;            // 32*64*64*64   =  8,388,608
    ushort_t* wr1  = zb   + 8388608;             //   4,096
    ushort_t* wr2  = wr1  + 4096;                // 131,072
    ushort_t* wr3  = wr2  + 131072;              //  73,728
    ushort_t* wd1  = wr3  + 73728;               // 131,072
    ushort_t* wd2  = wd1  + 131072;              // 131,072
    ushort_t* wd3  = wd2  + 131072;              //   9,216
    ushort_t* embb = wd3  + 9216;                //  32,768
    float*    se2  = (float*)(embb + 32768);     //     512 f32
    float*    lac  = se2 + 512;
    // x4 [32][258][258][4] = 8,520,192 aliases d2c (used only before decoder;
    // halo2_k zeros d2c halo AFTER conv1 consumed x4).
    ushort_t* x4   = d2c;

    repack_all<<<2007, 256, 0, stream>>>(w1, w2, w3, dw1, dw2, dw3, emb,
                                         wr1, wr2, wr3, wd1, wd2, wd3,
                                         embb, se2, lac);
    cast_x4 <<<8321, 256, 0, stream>>>(x, x4);
    halo3_k <<<1296, 256, 0, stream>>>(xp, h2p, qpad);

    conv1_mfma<<<4096, 256, 0, stream>>>(x4, wr1, b1, xp);
    conv2_mfma<<<2048, 256, 0, stream>>>(xp, wr2, b2, h2p);
    conv3_mfma<<<2048, 256, 0, stream>>>(h2p, wr3, b3, zb);
    vq_mfma   <<<512,  256, 0, stream>>>(zb, embb, emb, se2, qpad, lac);
    loss_fin_k<<<1, 1, 0, stream>>>(lac, xout + 6291456);

    halo2_k<<<515, 256, 0, stream>>>(d1c, d2c);

    for (int c0 = 0; c0 < 32; c0 += 8) {
        deconv1_mfma<<<1024, 256, 0, stream>>>(qpad + (size_t)c0 * 278784, wd1, db1, d1c);
        deconv2_mfma<<<2048, 256, 0, stream>>>(d1c, wd2, db2, d2c);
        deconv3_mfma<<<4096, 256, 0, stream>>>(d2c, wd3, db3, xout + (size_t)c0 * 196608);
    }
}

// Round 8
// 592.172 us; speedup vs baseline: 25.6043x; 1.2297x over previous
//
#include <hip/hip_runtime.h>
#include <math.h>

// ---------------------------------------------------------------------------
// VQ-VAE forward, round 7.
// vs round 6: (1) B(weight)-fragments hoisted into registers and loaded
// BEFORE the staging barrier (latency hidden); wave tiling re-shaped so each
// B-frag feeds 4-8 MFMAs (conv2 4mt x 2nt, conv3 4mt x 1nt, deconv1 4mt x 4nt,
// deconv2 8mt x 2nt); __launch_bounds__(256,2) raises VGPR cap (LDS caps
// occupancy at 2 blocks/CU anyway). (2) decoder chunks 8 -> 16 images by
// overlaying d1c16/d2c16 on dead encoder buffers; 12 decoder launches -> 6.
// MFMA 16x16x32 layouts (m89): A/B frag row=lane&15, k=(lane>>4)*8+j.
// C/D: col(n)=lane&15, row(m)=(lane>>4)*4+reg.
// ---------------------------------------------------------------------------

typedef __attribute__((ext_vector_type(8))) short bf16x8;
typedef __attribute__((ext_vector_type(4))) float fx4;
typedef unsigned short ushort_t;
#define MFMA16(a, b, c) __builtin_amdgcn_mfma_f32_16x16x32_bf16(a, b, c, 0, 0, 0)

__device__ inline ushort_t f2bf(float f) {
    unsigned u = __float_as_uint(f);
    u += 0x7FFFu + ((u >> 16) & 1u);
    return (ushort_t)(u >> 16);
}
__device__ inline float bf2f(ushort_t h) {
    return __uint_as_float(((unsigned)h) << 16);
}

__device__ __forceinline__ void stage16(const ushort_t* g, ushort_t* l) {
#if __has_builtin(__builtin_amdgcn_global_load_lds)
    __builtin_amdgcn_global_load_lds(
        (const __attribute__((address_space(1))) unsigned int*)g,
        (__attribute__((address_space(3))) unsigned int*)l, 16, 0, 0);
#else
    int lane = threadIdx.x & 63;
    *(int4*)(l + lane * 8) = *(const int4*)g;
#endif
}

__device__ __forceinline__ int swz(int s) { return s ^ ((s >> 3) & 7); }
__device__ __forceinline__ bf16x8 sld(const ushort_t* sm, int gslot) {
    return *(const bf16x8*)(sm + (size_t)swz(gslot) * 8);
}

__device__ __forceinline__ void halo_do(
    ushort_t* __restrict__ buf, int B, int H, int W, int C8, int idx)
{
    int perim = 2 * W + 2 * (H - 2);
    int c8 = idx % C8;
    int t = idx / C8;
    int p = t % perim;
    int b = t / perim;
    int r, col;
    if (p < W) { r = 0; col = p; }
    else if (p < 2 * W) { r = H - 1; col = p - W; }
    else { int pp = p - 2 * W; r = 1 + (pp >> 1); col = (pp & 1) ? (W - 1) : 0; }
    size_t off = ((((size_t)b * H + r) * W + col) * C8 + c8) * 8;
    *(int4*)(buf + off) = (int4){0, 0, 0, 0};
}

__global__ __launch_bounds__(256) void halo3_k(
    ushort_t* __restrict__ xp, ushort_t* __restrict__ h2p, ushort_t* __restrict__ qpad)
{
    int i = blockIdx.x * 256 + threadIdx.x;
    if (i < 132096) halo_do(xp, 32, 130, 130, 8, i);
    else if (i < 265216) halo_do(h2p, 32, 66, 66, 16, i - 132096);
    else if (i < 331776) halo_do(qpad, 32, 66, 66, 8, i - 265216);
}
// decoder halos (16-image buffers); runs after vq (xp/h2p/x4 dead)
__global__ __launch_bounds__(256) void halo2_k(
    ushort_t* __restrict__ d1c, ushort_t* __restrict__ d2c)
{
    int i = blockIdx.x * 256 + threadIdx.x;
    if (i < 132096) halo_do(d1c, 16, 130, 130, 16, i);
    else if (i < 263680) halo_do(d2c, 16, 258, 258, 8, i - 132096);
}

// x (32,3,256,256) f32 -> x4 [32][258][258][4] bf16 (ci=3 zero); + halo zero
__global__ __launch_bounds__(256) void cast_x4(
    const float* __restrict__ x, ushort_t* __restrict__ x4)
{
    if (blockIdx.x < 8192) {
        int i = blockIdx.x * 256 + threadIdx.x;
        int w = i & 255, h = (i >> 8) & 255, b = i >> 16;
        size_t base = ((size_t)b * 3 * 256 + h) * 256 + w;
        float v0 = x[base];
        float v1 = x[base + 65536];
        float v2 = x[base + 131072];
        uint2 o;
        o.x = (unsigned)f2bf(v0) | ((unsigned)f2bf(v1) << 16);
        o.y = (unsigned)f2bf(v2);
        *(uint2*)(x4 + ((size_t)(b * 258 + h + 1) * 258 + (w + 1)) * 4) = o;
    } else {
        int idx = (blockIdx.x - 8192) * 256 + threadIdx.x;
        if (idx >= 32 * 1032) return;
        int b = idx / 1032;
        int s = idx % 1032;
        int side = s / 258, c = s % 258;
        int r, col;
        if (side == 0) { r = 0; col = c; }
        else if (side == 1) { r = 257; col = c; }
        else if (side == 2) { r = c; col = 0; }
        else { r = c; col = 257; }
        *(uint2*)(x4 + ((size_t)(b * 258 + r) * 258 + col) * 4) = (uint2){0, 0};
    }
}

// ---------------- fused repack: all weights + embb + se2 + lac --------------
// swizzled weight layout: off = ((t*numC + c)*64 + lane)*8 + j ;
// co = t*16 + (lane&15); k = c*32 + (lane>>4)*8 + j
__global__ __launch_bounds__(256) void repack_all(
    const float* __restrict__ w1, const float* __restrict__ w2,
    const float* __restrict__ w3, const float* __restrict__ dw1,
    const float* __restrict__ dw2, const float* __restrict__ dw3,
    const float* __restrict__ emb,
    ushort_t* __restrict__ o1, ushort_t* __restrict__ o2,
    ushort_t* __restrict__ o3, ushort_t* __restrict__ od1,
    ushort_t* __restrict__ od2, ushort_t* __restrict__ od3,
    ushort_t* __restrict__ embb, float* __restrict__ se2,
    float* __restrict__ lac)
{
    int gi = blockIdx.x * 256 + threadIdx.x;
    if (gi < 4096) {                         // w1 [64co][3ci][4][4]
        int i = gi;
        int j = i & 7, lane = (i >> 3) & 63, tc = i >> 9;
        int c = tc & 1, t = tc >> 1;
        int co = t * 16 + (lane & 15);
        int k = c * 32 + (lane >> 4) * 8 + j;
        int kh = k >> 4, kw = (k >> 2) & 3, ci = k & 3;
        o1[i] = (ci < 3) ? f2bf(w1[((co * 3 + ci) * 4 + kh) * 4 + kw]) : (ushort_t)0;
    } else if (gi < 135168) {                // w2 [128co][64ci][4][4], numC=32
        int i = gi - 4096;
        int j = i & 7, lane = (i >> 3) & 63, tc = i >> 9;
        int c = tc & 31, t = tc >> 5;
        int co = t * 16 + (lane & 15);
        int k = c * 32 + (lane >> 4) * 8 + j;
        int tap = k >> 6, ci = k & 63, kh = tap >> 2, kw = tap & 3;
        o2[i] = f2bf(w2[((co * 64 + ci) * 4 + kh) * 4 + kw]);
    } else if (gi < 208896) {                // w3 [64co][128ci][3][3], numC=36
        int i = gi - 135168;
        int j = i & 7, lane = (i >> 3) & 63, tc = i >> 9;
        int c = tc % 36, t = tc / 36;
        int co = t * 16 + (lane & 15);
        int k = c * 32 + (lane >> 4) * 8 + j;
        int tap = k >> 7, ci = k & 127, kh = tap / 3, kw = tap % 3;
        o3[i] = f2bf(w3[((co * 128 + ci) * 3 + kh) * 3 + kw]);
    } else if (gi < 339968) {                // dw1 [64ci][128co][4][4], numC=32
        int i = gi - 208896;
        int j = i & 7, lane = (i >> 3) & 63, tc = i >> 9;
        int c = tc & 31, t = tc >> 5;
        int co = t * 16 + (lane & 15);
        int k = c * 32 + (lane >> 4) * 8 + j;
        int tap = k >> 6, ci = k & 63, kh = tap >> 2, kw = tap & 3;
        od1[i] = f2bf(dw1[((ci * 128 + co) * 4 + kh) * 4 + kw]);
    } else if (gi < 471040) {                // dw2 [128ci][64co][4][4], numC=64
        int i = gi - 339968;
        int j = i & 7, lane = (i >> 3) & 63, tc = i >> 9;
        int c = tc & 63, t = tc >> 6;
        int co = t * 16 + (lane & 15);
        int k = c * 32 + (lane >> 4) * 8 + j;
        int tap = k >> 7, ci = k & 127, kh = tap >> 2, kw = tap & 3;
        od2[i] = f2bf(dw2[((ci * 64 + co) * 4 + kh) * 4 + kw]);
    } else if (gi < 480256) {                // dw3 [64ci][3co][3][3], numC=18
        int i = gi - 471040;
        int j = i & 7, lane = (i >> 3) & 63, c = i >> 9;
        int co = lane & 15;
        int k = c * 32 + (lane >> 4) * 8 + j;
        int tap = k >> 6, ci = k & 63, kh = tap / 3, kw = tap % 3;
        od3[i] = (co < 3) ? f2bf(dw3[((ci * 3 + co) * 3 + kh) * 3 + kw]) : (ushort_t)0;
    } else if (gi < 513024) {                // embb [512n][64k] B-frag layout
        int i = gi - 480256;
        int j = i & 7, lane = (i >> 3) & 63, c = (i >> 9) & 1, nt = i >> 10;
        int n = nt * 16 + (lane & 15);
        int k = c * 32 + (lane >> 4) * 8 + j;
        embb[i] = f2bf(emb[n * 64 + k]);
    } else if (gi < 513536) {                // se2[512] fp32 |e|^2
        int n = gi - 513024;
        const float* e = emb + n * 64;
        float s = 0.f;
        for (int d = 0; d < 64; ++d) s = fmaf(e[d], e[d], s);
        se2[n] = s;
    } else if (gi == 513536) {
        lac[0] = 0.f;
    }
}

// ------------------------- conv1 MFMA ---------------------------------------
__global__ __launch_bounds__(256) void conv1_mfma(
    const ushort_t* __restrict__ x4, const ushort_t* __restrict__ wr,
    const float* __restrict__ bias, ushort_t* __restrict__ xp)
{
    __shared__ ushort_t sm[4608];
    int tid = threadIdx.x;
    int wv = tid >> 6, lane = tid & 63;
    int n16 = lane & 15, quad = lane >> 4;
    int blk = blockIdx.x;                   // 4096
    int oh = blk & 127, b = blk >> 7;
    const ushort_t* gsrc = x4 + (size_t)(b * 258 + 2 * oh) * 1032;
    int sl = lane ^ ((lane >> 3) & 7);
    // hoist all B-frags before staging (latency overlaps barrier)
    bf16x8 bfr[4][2];
    #pragma unroll
    for (int nt = 0; nt < 4; ++nt)
        #pragma unroll
        for (int c = 0; c < 2; ++c)
            bfr[nt][c] = *(const bf16x8*)(wr + ((size_t)(nt * 2 + c) * 64 + lane) * 8);
    for (int u = wv; u < 9; u += 4)
        stage16(gsrc + u * 512 + sl * 8, sm + u * 512);
    __syncthreads();

    fx4 acc[2][4];
    #pragma unroll
    for (int i = 0; i < 2; ++i)
        #pragma unroll
        for (int j = 0; j < 4; ++j) acc[i][j] = (fx4){0.f, 0.f, 0.f, 0.f};
    #pragma unroll
    for (int c = 0; c < 2; ++c) {
        int kh = 2 * c + (quad >> 1);
        int kwh = quad & 1;
        bf16x8 af[2];
        #pragma unroll
        for (int mt = 0; mt < 2; ++mt) {
            int ow = (wv * 2 + mt) * 16 + n16;
            af[mt] = sld(sm, kh * 129 + ow + kwh);
        }
        #pragma unroll
        for (int mt = 0; mt < 2; ++mt)
            #pragma unroll
            for (int nt = 0; nt < 4; ++nt)
                acc[mt][nt] = MFMA16(af[mt], bfr[nt][c], acc[mt][nt]);
    }
    #pragma unroll
    for (int nt = 0; nt < 4; ++nt) {
        int co = nt * 16 + n16;
        float bs = bias[co];
        #pragma unroll
        for (int mt = 0; mt < 2; ++mt) {
            #pragma unroll
            for (int r = 0; r < 4; ++r) {
                int ow = (wv * 2 + mt) * 16 + quad * 4 + r;
                xp[((size_t)(b * 130 + oh + 1) * 130 + (ow + 1)) * 64 + co] =
                    f2bf(fmaxf(acc[mt][nt][r] + bs, 0.f));
            }
        }
    }
}

// ------------------------- conv2 MFMA ---------------------------------------
// Wave: 4mt x 2nt (nt tiles wv*2, wv*2+1). B in rotating quarter-buffers
// (8 steps x 2nt), first quarter loaded before the staging barrier.
__global__ __launch_bounds__(256, 2) void conv2_mfma(
    const ushort_t* __restrict__ xp, const ushort_t* __restrict__ wr,
    const float* __restrict__ bias, ushort_t* __restrict__ h2p)
{
    __shared__ ushort_t sm[33280];
    int tid = threadIdx.x;
    int wv = tid >> 6, lane = tid & 63;
    int n16 = lane & 15, quad = lane >> 4;
    int blk = blockIdx.x;                   // 2048
    int oh = blk & 63, b = blk >> 6;
    const ushort_t* gsrc = xp + (size_t)(b * 130 + 2 * oh) * 130 * 64;
    int sl = lane ^ ((lane >> 3) & 7);
    const ushort_t* w0 = wr + ((size_t)(wv * 2 + 0) * 32 * 64 + lane) * 8;
    const ushort_t* w1 = wr + ((size_t)(wv * 2 + 1) * 32 * 64 + lane) * 8;

    bf16x8 Bq[2][16];
    #pragma unroll
    for (int s = 0; s < 8; ++s) {
        Bq[0][2 * s]     = *(const bf16x8*)(w0 + (size_t)s * 512);
        Bq[0][2 * s + 1] = *(const bf16x8*)(w1 + (size_t)s * 512);
    }
    for (int u = wv; u < 65; u += 4)
        stage16(gsrc + (size_t)u * 512 + sl * 8, sm + u * 512);
    __syncthreads();

    fx4 acc[4][2];
    #pragma unroll
    for (int i = 0; i < 4; ++i)
        #pragma unroll
        for (int j = 0; j < 2; ++j) acc[i][j] = (fx4){0.f, 0.f, 0.f, 0.f};
    #pragma unroll
    for (int qb = 0; qb < 4; ++qb) {
        int cur = qb & 1;
        if (qb < 3) {
            #pragma unroll
            for (int s = 0; s < 8; ++s) {
                int st = (qb + 1) * 8 + s;
                Bq[cur ^ 1][2 * s]     = *(const bf16x8*)(w0 + (size_t)st * 512);
                Bq[cur ^ 1][2 * s + 1] = *(const bf16x8*)(w1 + (size_t)st * 512);
            }
        }
        #pragma unroll
        for (int s = 0; s < 8; ++s) {
            int step = qb * 8 + s, tap = step >> 1, ks = step & 1;
            int kh = tap >> 2, kw = tap & 3;
            bf16x8 af[4];
            #pragma unroll
            for (int mt = 0; mt < 4; ++mt) {
                int px = kw + 2 * (mt * 16 + n16);              // 0..129
                af[mt] = sld(sm, (kh * 130 + px) * 8 + ks * 4 + quad);
            }
            #pragma unroll
            for (int mt = 0; mt < 4; ++mt) {
                acc[mt][0] = MFMA16(af[mt], Bq[cur][2 * s], acc[mt][0]);
                acc[mt][1] = MFMA16(af[mt], Bq[cur][2 * s + 1], acc[mt][1]);
            }
        }
    }
    #pragma unroll
    for (int nt = 0; nt < 2; ++nt) {
        int co = (wv * 2 + nt) * 16 + n16;
        float bs = bias[co];
        #pragma unroll
        for (int mt = 0; mt < 4; ++mt) {
            #pragma unroll
            for (int r = 0; r < 4; ++r) {
                int ow = mt * 16 + quad * 4 + r;
                h2p[((size_t)(b * 66 + oh + 1) * 66 + (ow + 1)) * 128 + co] =
                    f2bf(fmaxf(acc[mt][nt][r] + bs, 0.f));
            }
        }
    }
}

// ------------------------- conv3 MFMA ---------------------------------------
// Wave: 4mt x 1nt (nt tile = wv). All 36 B-frags hoisted before barrier.
__global__ __launch_bounds__(256, 2) void conv3_mfma(
    const ushort_t* __restrict__ hp, const ushort_t* __restrict__ wr,
    const float* __restrict__ bias, ushort_t* __restrict__ z)
{
    __shared__ ushort_t sm[25600];
    int tid = threadIdx.x;
    int wv = tid >> 6, lane = tid & 63;
    int n16 = lane & 15, quad = lane >> 4;
    int blk = blockIdx.x;                   // 2048
    int oh = blk & 63, b = blk >> 6;
    const ushort_t* gsrc = hp + (size_t)(b * 66 + oh) * 66 * 128;
    int sl = lane ^ ((lane >> 3) & 7);
    const ushort_t* wb = wr + ((size_t)wv * 36 * 64 + lane) * 8;
    bf16x8 Bb[36];
    #pragma unroll
    for (int s = 0; s < 36; ++s)
        Bb[s] = *(const bf16x8*)(wb + (size_t)s * 512);
    for (int u = wv; u < 50; u += 4)
        stage16(gsrc + (size_t)u * 512 + sl * 8, sm + u * 512);
    __syncthreads();

    fx4 acc[4];
    #pragma unroll
    for (int i = 0; i < 4; ++i) acc[i] = (fx4){0.f, 0.f, 0.f, 0.f};
    #pragma unroll
    for (int tap = 0; tap < 9; ++tap) {
        int kh = tap / 3, kw = tap % 3;
        #pragma unroll
        for (int ks = 0; ks < 4; ++ks) {
            bf16x8 af[4];
            #pragma unroll
            for (int mt = 0; mt < 4; ++mt) {
                int px = kw + mt * 16 + n16;                    // 0..65
                af[mt] = sld(sm, (kh * 66 + px) * 16 + ks * 4 + quad);
            }
            #pragma unroll
            for (int mt = 0; mt < 4; ++mt)
                acc[mt] = MFMA16(af[mt], Bb[tap * 4 + ks], acc[mt]);
        }
    }
    int co = wv * 16 + n16;
    float bs = bias[co];
    #pragma unroll
    for (int mt = 0; mt < 4; ++mt) {
        #pragma unroll
        for (int r = 0; r < 4; ++r) {
            int ow = mt * 16 + quad * 4 + r;
            z[((size_t)(b * 64 + oh) * 64 + ow) * 64 + co] =
                f2bf(fmaxf(acc[mt][r] + bs, 0.f));
        }
    }
}

// ------------------------- VQ MFMA ------------------------------------------
__global__ __launch_bounds__(256) void vq_mfma(
    const ushort_t* __restrict__ z, const ushort_t* __restrict__ embb,
    const float* __restrict__ emb, const float* __restrict__ se2g,
    ushort_t* __restrict__ qpad, float* __restrict__ loss_acc)
{
    __shared__ ushort_t smz[16384];
    __shared__ float sse2[512];
    __shared__ float red[256];
    int tid = threadIdx.x;
    int wv = tid >> 6, lane = tid & 63;
    int n16 = lane & 15, quad = lane >> 4;
    int blk = blockIdx.x;                   // 512
    const ushort_t* gsrc = z + (size_t)blk * 16384;
    int sl = lane ^ ((lane >> 3) & 7);
    for (int u = wv; u < 32; u += 4)
        stage16(gsrc + (size_t)u * 512 + sl * 8, smz + u * 512);
    for (int i = tid; i < 512; i += 256) sse2[i] = se2g[i];
    __syncthreads();

    bf16x8 a[4][2];
    #pragma unroll
    for (int mt = 0; mt < 4; ++mt)
        #pragma unroll
        for (int ks = 0; ks < 2; ++ks)
            a[mt][ks] = sld(smz, (wv * 64 + mt * 16 + n16) * 8 + ks * 4 + quad);

    float best[4][4];
    int bid[4][4];
    #pragma unroll
    for (int mt = 0; mt < 4; ++mt)
        #pragma unroll
        for (int r = 0; r < 4; ++r) { best[mt][r] = 1e30f; bid[mt][r] = 0; }

    for (int nt = 0; nt < 32; ++nt) {
        bf16x8 b0 = *(const bf16x8*)(embb + ((size_t)(nt * 2 + 0) * 64 + lane) * 8);
        bf16x8 b1 = *(const bf16x8*)(embb + ((size_t)(nt * 2 + 1) * 64 + lane) * 8);
        float s2 = sse2[nt * 16 + n16];
        int myn = nt * 16 + n16;
        #pragma unroll
        for (int mt = 0; mt < 4; ++mt) {
            fx4 acc = (fx4){0.f, 0.f, 0.f, 0.f};
            acc = MFMA16(a[mt][0], b0, acc);
            acc = MFMA16(a[mt][1], b1, acc);
            #pragma unroll
            for (int r = 0; r < 4; ++r) {
                float sc = fmaf(-2.f, acc[r], s2);
                if (sc < best[mt][r]) { best[mt][r] = sc; bid[mt][r] = myn; }
            }
        }
    }

    float lsum = 0.f;
    #pragma unroll
    for (int mt = 0; mt < 4; ++mt) {
        #pragma unroll
        for (int r = 0; r < 4; ++r) {
            float bs = best[mt][r];
            int bi = bid[mt][r];
            #pragma unroll
            for (int st = 1; st < 16; st <<= 1) {
                float os = __shfl_xor(bs, st, 64);
                int oi = __shfl_xor(bi, st, 64);
                if (os < bs || (os == bs && oi < bi)) { bs = os; bi = oi; }
            }
            int ml = wv * 64 + mt * 16 + quad * 4 + r;
            int pos = blk * 256 + ml;
            int b = pos >> 12, h = (pos >> 6) & 63, w = pos & 63;
            float4 ev = *(const float4*)(emb + (size_t)bi * 64 + n16 * 4);
            int slot = ml * 8 + (n16 >> 1);
            const ushort_t* zp = smz + (size_t)swz(slot) * 8 + (n16 & 1) * 4;
            float d0 = ev.x - bf2f(zp[0]);
            float d1 = ev.y - bf2f(zp[1]);
            float d2 = ev.z - bf2f(zp[2]);
            float d3 = ev.w - bf2f(zp[3]);
            lsum = fmaf(d0, d0, lsum);
            lsum = fmaf(d1, d1, lsum);
            lsum = fmaf(d2, d2, lsum);
            lsum = fmaf(d3, d3, lsum);
            uint2 o;
            o.x = (unsigned)f2bf(ev.x) | ((unsigned)f2bf(ev.y) << 16);
            o.y = (unsigned)f2bf(ev.z) | ((unsigned)f2bf(ev.w) << 16);
            *(uint2*)(qpad + ((size_t)(b * 66 + h + 1) * 66 + (w + 1)) * 64 + n16 * 4) = o;
        }
    }
    red[tid] = lsum;
    __syncthreads();
    for (int s = 128; s > 0; s >>= 1) {
        if (tid < s) red[tid] += red[tid + s];
        __syncthreads();
    }
    if (tid == 0) atomicAdd(loss_acc, red[0]);
}

__global__ void loss_fin_k(const float* __restrict__ acc, float* __restrict__ out)
{
    out[0] = 1.25f * acc[0] / 8388608.0f;
}

// ------------------------- deconv1 MFMA -------------------------------------
// Wave: parity=wv&1, ng=wv>>1 (4 nt tiles each). All 32 B-frags pre-barrier.
__global__ __launch_bounds__(256, 2) void deconv1_mfma(
    const ushort_t* __restrict__ q, const ushort_t* __restrict__ wr,
    const float* __restrict__ bias, ushort_t* __restrict__ d1)
{
    __shared__ ushort_t sm[8704];
    int tid = threadIdx.x;
    int wv = tid >> 6, lane = tid & 63;
    int n16 = lane & 15, quad = lane >> 4;
    int blk = blockIdx.x;                   // 2048
    int oh = blk & 127, b = blk >> 7;       // b 0..15
    int h0 = (oh + 1) & 1;
    int ihp0 = ((oh + 1 - h0) >> 1) + 1;
    const ushort_t* gsrc = q + (size_t)(b * 66 + ihp0 - 1) * 66 * 64;
    int sl = lane ^ ((lane >> 3) & 7);
    int pw = wv & 1, ng = wv >> 1;
    int q0 = 1 - pw;
    // hoist all B: nt 0..3, steps (t2,t3,ks) = 8
    bf16x8 Bb[4][8];
    #pragma unroll
    for (int nt = 0; nt < 4; ++nt) {
        const ushort_t* wb = wr + ((size_t)(ng * 4 + nt) * 32 * 64 + lane) * 8;
        #pragma unroll
        for (int t2 = 0; t2 < 2; ++t2)
            #pragma unroll
            for (int t3 = 0; t3 < 2; ++t3)
                #pragma unroll
                for (int ks = 0; ks < 2; ++ks) {
                    int tap = (h0 + 2 * t2) * 4 + (q0 + 2 * t3);
                    Bb[nt][t2 * 4 + t3 * 2 + ks] =
                        *(const bf16x8*)(wb + (size_t)(tap * 2 + ks) * 512);
                }
    }
    for (int u = wv; u < 17; u += 4)
        stage16(gsrc + (size_t)u * 512 + sl * 8, sm + u * 512);
    __syncthreads();

    fx4 acc[4][4];
    #pragma unroll
    for (int i = 0; i < 4; ++i)
        #pragma unroll
        for (int j = 0; j < 4; ++j) acc[i][j] = (fx4){0.f, 0.f, 0.f, 0.f};
    #pragma unroll
    for (int t2 = 0; t2 < 2; ++t2) {
        int lrow = 1 - t2;
        #pragma unroll
        for (int t3 = 0; t3 < 2; ++t3) {
            int cadd = pw + (t3 == 0 ? 1 : 0);
            #pragma unroll
            for (int ks = 0; ks < 2; ++ks) {
                bf16x8 af[4];
                #pragma unroll
                for (int mt = 0; mt < 4; ++mt) {
                    int px = cadd + mt * 16 + n16;              // 0..65
                    af[mt] = sld(sm, (lrow * 66 + px) * 8 + ks * 4 + quad);
                }
                #pragma unroll
                for (int mt = 0; mt < 4; ++mt)
                    #pragma unroll
                    for (int nt = 0; nt < 4; ++nt)
                        acc[mt][nt] = MFMA16(af[mt], Bb[nt][t2 * 4 + t3 * 2 + ks], acc[mt][nt]);
            }
        }
    }
    #pragma unroll
    for (int nt = 0; nt < 4; ++nt) {
        int co = (ng * 4 + nt) * 16 + n16;
        float bs = bias[co];
        #pragma unroll
        for (int mt = 0; mt < 4; ++mt) {
            #pragma unroll
            for (int r = 0; r < 4; ++r) {
                int ow = 2 * (mt * 16 + quad * 4 + r) + pw;
                d1[((size_t)(b * 130 + oh + 1) * 130 + (ow + 1)) * 128 + co] =
                    f2bf(fmaxf(acc[mt][nt][r] + bs, 0.f));
            }
        }
    }
}

// ------------------------- deconv2 MFMA -------------------------------------
// Wave: parity=wv&1, ng=wv>>1 (2 nt tiles each), 8 mt. All 32 B pre-barrier.
__global__ __launch_bounds__(256, 2) void deconv2_mfma(
    const ushort_t* __restrict__ d1, const ushort_t* __restrict__ wr,
    const float* __restrict__ bias, ushort_t* __restrict__ d2)
{
    __shared__ ushort_t sm[33280];
    int tid = threadIdx.x;
    int wv = tid >> 6, lane = tid & 63;
    int n16 = lane & 15, quad = lane >> 4;
    int blk = blockIdx.x;                   // 4096
    int oh = blk & 255, b = blk >> 8;       // b 0..15
    int h0 = (oh + 1) & 1;
    int ihp0 = ((oh + 1 - h0) >> 1) + 1;
    const ushort_t* gsrc = d1 + (size_t)(b * 130 + ihp0 - 1) * 130 * 128;
    int sl = lane ^ ((lane >> 3) & 7);
    int pw = wv & 1, ng = wv >> 1;
    int q0 = 1 - pw;
    // hoist all B: nt 0..1, steps (t2,t3,ks4) = 16
    bf16x8 Bb[2][16];
    #pragma unroll
    for (int nt = 0; nt < 2; ++nt) {
        const ushort_t* wb = wr + ((size_t)(ng * 2 + nt) * 64 * 64 + lane) * 8;
        #pragma unroll
        for (int t2 = 0; t2 < 2; ++t2)
            #pragma unroll
            for (int t3 = 0; t3 < 2; ++t3) {
                int tap = (h0 + 2 * t2) * 4 + (q0 + 2 * t3);
                #pragma unroll
                for (int ks = 0; ks < 4; ++ks)
                    Bb[nt][t2 * 8 + t3 * 4 + ks] =
                        *(const bf16x8*)(wb + (size_t)(tap * 4 + ks) * 512);
            }
    }
    for (int u = wv; u < 65; u += 4)
        stage16(gsrc + (size_t)u * 512 + sl * 8, sm + u * 512);
    __syncthreads();

    fx4 acc[8][2];
    #pragma unroll
    for (int i = 0; i < 8; ++i)
        #pragma unroll
        for (int j = 0; j < 2; ++j) acc[i][j] = (fx4){0.f, 0.f, 0.f, 0.f};
    #pragma unroll
    for (int t2 = 0; t2 < 2; ++t2) {
        int lrow = 1 - t2;
        #pragma unroll
        for (int t3 = 0; t3 < 2; ++t3) {
            int cadd = pw + (t3 == 0 ? 1 : 0);
            #pragma unroll
            for (int ks = 0; ks < 4; ++ks) {
                #pragma unroll
                for (int mt = 0; mt < 8; ++mt) {
                    int px = cadd + mt * 16 + n16;              // 0..129
                    bf16x8 af = sld(sm, (lrow * 130 + px) * 16 + ks * 4 + quad);
                    acc[mt][0] = MFMA16(af, Bb[0][t2 * 8 + t3 * 4 + ks], acc[mt][0]);
                    acc[mt][1] = MFMA16(af, Bb[1][t2 * 8 + t3 * 4 + ks], acc[mt][1]);
                }
            }
        }
    }
    #pragma unroll
    for (int nt = 0; nt < 2; ++nt) {
        int co = (ng * 2 + nt) * 16 + n16;
        float bs = bias[co];
        #pragma unroll
        for (int mt = 0; mt < 8; ++mt) {
            #pragma unroll
            for (int r = 0; r < 4; ++r) {
                int ow = 2 * (mt * 16 + quad * 4 + r) + pw;
                d2[((size_t)(b * 258 + oh + 1) * 258 + (ow + 1)) * 64 + co] =
                    f2bf(fmaxf(acc[mt][nt][r] + bs, 0.f));
            }
        }
    }
}

// ------------------------- deconv3 MFMA -------------------------------------
__global__ __launch_bounds__(256) void deconv3_mfma(
    const ushort_t* __restrict__ d2, const ushort_t* __restrict__ wr,
    const float* __restrict__ bias, float* __restrict__ out)
{
    __shared__ ushort_t sm[26112];
    int tid = threadIdx.x;
    int wv = tid >> 6, lane = tid & 63;
    int n16 = lane & 15, quad = lane >> 4;
    int blk = blockIdx.x;                   // 8192
    int half = blk & 1;
    int oh = (blk >> 1) & 255;
    int b = blk >> 9;                       // b 0..15
    int sl = lane ^ ((lane >> 3) & 7);
    bf16x8 Bb[18];
    #pragma unroll
    for (int s = 0; s < 18; ++s)
        Bb[s] = *(const bf16x8*)(wr + ((size_t)s * 64 + lane) * 8);
    for (int u = wv; u < 51; u += 4) {
        int c = u / 17, uu = u - c * 17;
        const ushort_t* gsrc = d2 + ((size_t)(b * 258 + oh + c) * 258 + half * 128) * 64;
        stage16(gsrc + (size_t)uu * 512 + sl * 8, sm + c * 8704 + uu * 512);
    }
    __syncthreads();

    fx4 acc[2];
    #pragma unroll
    for (int i = 0; i < 2; ++i) acc[i] = (fx4){0.f, 0.f, 0.f, 0.f};
    #pragma unroll
    for (int tap = 0; tap < 9; ++tap) {
        int kh = tap / 3, kw = tap % 3;
        int c = 2 - kh;
        #pragma unroll
        for (int ks = 0; ks < 2; ++ks) {
            bf16x8 af[2];
            #pragma unroll
            for (int mt = 0; mt < 2; ++mt) {
                int px = (2 - kw) + (wv * 2 + mt) * 16 + n16;   // 0..129
                af[mt] = sld(sm, c * 1088 + px * 8 + ks * 4 + quad);
            }
            #pragma unroll
            for (int mt = 0; mt < 2; ++mt)
                acc[mt] = MFMA16(af[mt], Bb[tap * 2 + ks], acc[mt]);
        }
    }
    int co = n16;
    if (co < 3) {
        float bs = bias[co];
        #pragma unroll
        for (int mt = 0; mt < 2; ++mt) {
            int ow0 = half * 128 + (wv * 2 + mt) * 16 + quad * 4;
            float4 v;
            v.x = 1.f / (1.f + __expf(-(acc[mt][0] + bs)));
            v.y = 1.f / (1.f + __expf(-(acc[mt][1] + bs)));
            v.z = 1.f / (1.f + __expf(-(acc[mt][2] + bs)));
            v.w = 1.f / (1.f + __expf(-(acc[mt][3] + bs)));
            *(float4*)(out + (((size_t)b * 3 + co) * 256 + oh) * 256 + ow0) = v;
        }
    }
}

// ---------------------------------------------------------------------------
extern "C" void kernel_launch(void* const* d_in, const int* in_sizes, int n_in,
                              void* d_out, int out_size, void* d_ws, size_t ws_size,
                              hipStream_t stream)
{
    const float* x   = (const float*)d_in[0];
    const float* w1  = (const float*)d_in[1];
    const float* b1  = (const float*)d_in[2];
    const float* w2  = (const float*)d_in[3];
    const float* b2  = (const float*)d_in[4];
    const float* w3  = (const float*)d_in[5];
    const float* b3  = (const float*)d_in[6];
    const float* emb = (const float*)d_in[7];
    const float* dw1 = (const float*)d_in[8];
    const float* db1 = (const float*)d_in[9];
    const float* dw2 = (const float*)d_in[10];
    const float* db2 = (const float*)d_in[11];
    const float* dw3 = (const float*)d_in[12];
    const float* db3 = (const float*)d_in[13];
    float* xout = (float*)d_out;

    // shared region (102,772,736): encoder xp|h2p overlaid by decoder d1c16|d2c16
    ushort_t* shared = (ushort_t*)d_ws;
    ushort_t* xp   = shared;                     // 34,611,200
    ushort_t* h2p  = shared + 34611200;          // 17,842,176
    ushort_t* d1c  = shared;                     // 16*130*130*128 = 34,611,200
    ushort_t* d2c  = shared + 34611200;          // 16*258*258*64  = 68,161,536
    ushort_t* x4   = shared + 94252544;          // 8,520,192 (tail of d2c region)
    ushort_t* zb   = shared + 102772736;         // 8,388,608
    ushort_t* qpad = zb + 8388608;               // 8,921,088
    ushort_t* wr1  = qpad + 8921088;             //   4,096
    ushort_t* wr2  = wr1  + 4096;                // 131,072
    ushort_t* wr3  = wr2  + 131072;              //  73,728
    ushort_t* wd1  = wr3  + 73728;               // 131,072
    ushort_t* wd2  = wd1  + 131072;              // 131,072
    ushort_t* wd3  = wd2  + 131072;              //   9,216
    ushort_t* embb = wd3  + 9216;                //  32,768
    float*    se2  = (float*)(embb + 32768);     //     512 f32
    float*    lac  = se2 + 512;

    repack_all<<<2007, 256, 0, stream>>>(w1, w2, w3, dw1, dw2, dw3, emb,
                                         wr1, wr2, wr3, wd1, wd2, wd3,
                                         embb, se2, lac);
    cast_x4 <<<8321, 256, 0, stream>>>(x, x4);
    halo3_k <<<1296, 256, 0, stream>>>(xp, h2p, qpad);

    conv1_mfma<<<4096, 256, 0, stream>>>(x4, wr1, b1, xp);
    conv2_mfma<<<2048, 256, 0, stream>>>(xp, wr2, b2, h2p);
    conv3_mfma<<<2048, 256, 0, stream>>>(h2p, wr3, b3, zb);
    vq_mfma   <<<512,  256, 0, stream>>>(zb, embb, emb, se2, qpad, lac);
    loss_fin_k<<<1, 1, 0, stream>>>(lac, xout + 6291456);

    halo2_k<<<1030, 256, 0, stream>>>(d1c, d2c);

    for (int c0 = 0; c0 < 32; c0 += 16) {
        deconv1_mfma<<<2048, 256, 0, stream>>>(qpad + (size_t)c0 * 278784, wd1, db1, d1c);
        deconv2_mfma<<<4096, 256, 0, stream>>>(d1c, wd2, db2, d2c);
        deconv3_mfma<<<8192, 256, 0, stream>>>(d2c, wd3, db3, xout + (size_t)c0 * 196608);
    }
}